// Round 5
// baseline (687.897 us; speedup 1.0000x reference)
//
#include <hip/hip_runtime.h>

#define N_NODES 50000
#define N_EDGES 800000
#define C 64
#define N_GRAPHS 64

#define NBKT 256                          // coarse buckets
#define NPB 196                           // nodes per bucket (255*196=49980; last bucket holds 20)
#define NB 512                            // bucketing grid
#define EPB ((N_EDGES + NB - 1) / NB)     // 1563 edges per block

// ---------------- workspace layout (bytes, 256-aligned) ----------------
#define OFF_BB     0u          // bucketBase: (NBKT+1) ints
#define OFF_EPK    1280u       // packed edges: N_EDGES ints  (src | dst_local<<16)
#define OFF_AGG    3201280u    // N_NODES*64 floats (also h2 in-place; hist_g aliases head)
#define OFF_H1     16001280u   // N_NODES*64 floats
#define OFF_POOLED 28801280u   // N_GRAPHS*2 uints
// total ~28.8 MB; hist_g (NBKT*NB ints = 512 KB) aliases OFF_AGG (dead by then)

// ---------------- pass 1a: per-block bucket histogram ----------------
__global__ __launch_bounds__(256) void bucket_hist_kernel(const int* __restrict__ dst,
                                                          int* __restrict__ hist_g) {
    __shared__ int h[NBKT];
    const int t = threadIdx.x;
    const int blk = blockIdx.x;
    h[t] = 0;                      // blockDim == NBKT == 256
    __syncthreads();
    const int beg = blk * EPB;
    const int end = min(beg + EPB, N_EDGES);
    for (int i = beg + t; i < end; i += 256)
        atomicAdd(&h[dst[i] / NPB], 1);
    __syncthreads();
    hist_g[t * NB + blk] = h[t];   // bucket-major for the scan
}

// ---------------- pass 1b: exclusive scan of hist_g (131072) + bucket bases ----------------
__global__ __launch_bounds__(1024) void bucket_scan_kernel(int* __restrict__ hist_g,
                                                           int* __restrict__ bucketBase) {
    __shared__ int s[1024];
    const int t = threadIdx.x;
    const int PT = (NBKT * NB) / 1024;   // 128 elements per thread
    const int base = t * PT;
    int local = 0;
    for (int k = 0; k < PT; k++) local += hist_g[base + k];
    s[t] = local;
    __syncthreads();
    for (int off = 1; off < 1024; off <<= 1) {
        int v = 0;
        if (t >= off) v = s[t - off];
        __syncthreads();
        if (t >= off) s[t] += v;
        __syncthreads();
    }
    int run = s[t] - local;              // exclusive prefix for this thread's range
    for (int k = 0; k < PT; k++) {
        int e = base + k;
        int v = hist_g[e];
        if ((e & (NB - 1)) == 0) bucketBase[e / NB] = run;  // bucket start
        hist_g[e] = run;
        run += v;
    }
    if (t == 0) bucketBase[NBKT] = N_EDGES;
}

// ---------------- pass 1c: scatter packed edges into bucket order ----------------
__global__ __launch_bounds__(256) void bucket_scatter_kernel(const int* __restrict__ src,
                                                             const int* __restrict__ dst,
                                                             const int* __restrict__ hist_g,
                                                             int* __restrict__ epk) {
    __shared__ int cur[NBKT];
    const int t = threadIdx.x;
    const int blk = blockIdx.x;
    cur[t] = hist_g[t * NB + blk];
    __syncthreads();
    const int beg = blk * EPB;
    const int end = min(beg + EPB, N_EDGES);
    for (int i = beg + t; i < end; i += 256) {
        int d = dst[i];
        int b = d / NPB;
        int pos = atomicAdd(&cur[b], 1);
        epk[pos] = src[i] | ((d - b * NPB) << 16);   // src < 65536, local < 196
    }
}

// ---------------- aggregation: one block per bucket, LDS accumulator ----------------
// agg[dst] += h[src] for all edges of the bucket; lane = feature.
__global__ __launch_bounds__(1024) void agg_kernel(const float* __restrict__ h,
                                                   const int* __restrict__ epk,
                                                   const int* __restrict__ bucketBase,
                                                   float* __restrict__ agg) {
    __shared__ float aggL[NPB * C];      // 49 KB
    const int t = threadIdx.x;
    const int blk = blockIdx.x;
    const float4 z4 = {0.f, 0.f, 0.f, 0.f};
    for (int i = t * 4; i < NPB * C; i += 4096) *(float4*)&aggL[i] = z4;
    __syncthreads();
    const int base = bucketBase[blk];
    const int endE = bucketBase[blk + 1];
    const int w = t >> 6, lane = t & 63;  // 16 waves
    for (int e0 = base + w * 4; e0 < endE; e0 += 64) {
        int pk[4]; float v[4];
        #pragma unroll
        for (int u = 0; u < 4; u++)
            pk[u] = (e0 + u < endE) ? epk[e0 + u] : -1;
        #pragma unroll
        for (int u = 0; u < 4; u++)
            if (pk[u] >= 0) v[u] = h[(size_t)(pk[u] & 0xFFFF) * C + lane];
        #pragma unroll
        for (int u = 0; u < 4; u++)
            if (pk[u] >= 0) atomicAdd(&aggL[(pk[u] >> 16) * C + lane], v[u]);
    }
    __syncthreads();
    const int node0 = blk * NPB;
    const int nn = min(NPB, N_NODES - node0);
    for (int i = t * 4; i < nn * C; i += 4096)
        *(float4*)&agg[(size_t)node0 * C + i] = *(const float4*)&aggL[i];
}

// ---------------- fused double-GEMM + bias + relu ----------------
// out = relu(A @ Wr + B @ Wl + bias). `out` may alias B (rows block-private,
// staged through LDS before write).
__global__ __launch_bounds__(256) void gemm_kernel(const float* __restrict__ A,
                                                   const float* __restrict__ B,
                                                   const float* __restrict__ Wr,
                                                   const float* __restrict__ Wl,
                                                   const float* __restrict__ bias,
                                                   float* out) {
    __shared__ float Wrs[64 * 64];
    __shared__ float Wls[64 * 64];
    __shared__ float As[64 * 65];
    __shared__ float Bs[64 * 65];
    const int t = threadIdx.x;
    const int row0 = blockIdx.x * 64;
    for (int i = t * 4; i < 4096; i += 1024) {
        *(float4*)&Wrs[i] = *(const float4*)&Wr[i];
        *(float4*)&Wls[i] = *(const float4*)&Wl[i];
    }
    const int r = t >> 2;
    const int q = t & 3;
    const int grow = row0 + r;
    if (grow < N_NODES) {
        #pragma unroll
        for (int c = 0; c < 4; c++) {
            *(float4*)&As[r * 65 + q * 16 + c * 4] =
                *(const float4*)&A[(size_t)grow * C + q * 16 + c * 4];
            *(float4*)&Bs[r * 65 + q * 16 + c * 4] =
                *(const float4*)&B[(size_t)grow * C + q * 16 + c * 4];
        }
    }
    __syncthreads();
    const int f0 = q * 16;
    float acc[16];
    #pragma unroll
    for (int ff = 0; ff < 16; ff++) acc[ff] = bias[f0 + ff];
    for (int k = 0; k < 64; k++) {
        float a = As[r * 65 + k];
        float b = Bs[r * 65 + k];
        #pragma unroll
        for (int ff = 0; ff < 16; ff++)
            acc[ff] += a * Wrs[k * 64 + f0 + ff] + b * Wls[k * 64 + f0 + ff];
    }
    if (grow < N_NODES) {
        #pragma unroll
        for (int ff = 0; ff < 16; ff += 4) {
            float4 v;
            v.x = fmaxf(acc[ff + 0], 0.f);
            v.y = fmaxf(acc[ff + 1], 0.f);
            v.z = fmaxf(acc[ff + 2], 0.f);
            v.w = fmaxf(acc[ff + 3], 0.f);
            *(float4*)&out[(size_t)grow * C + f0 + ff] = v;
        }
    }
}

// ---------------- head: mid softmax + fc1 + fc2 + segment_max ----------------
__global__ __launch_bounds__(256) void head_kernel(const float* __restrict__ h2,
                                                   const int* __restrict__ batch,
                                                   const float* __restrict__ fc1w,
                                                   const float* __restrict__ fc1b,
                                                   const float* __restrict__ fc2w,
                                                   const float* __restrict__ fc2b,
                                                   float* __restrict__ mid_out,
                                                   unsigned int* __restrict__ pooled) {
    __shared__ float w1[64 * 8];
    __shared__ float b1s[8];
    __shared__ float w2[16];
    __shared__ float b2s[2];
    __shared__ unsigned int pool_s[N_GRAPHS * 2];
    const int t = threadIdx.x;
    for (int i = t; i < 512; i += 256) w1[i] = fc1w[i];
    if (t < 8) b1s[t] = fc1b[t];
    if (t < 16) w2[t] = fc2w[t];
    if (t < 2) b2s[t] = fc2b[t];
    if (t < N_GRAPHS * 2) pool_s[t] = 0u;
    __syncthreads();
    const int i = blockIdx.x * 256 + t;
    int b = -1;
    unsigned int u0 = 0u, u1 = 0u;
    if (i < N_NODES) {
        float row[64];
        #pragma unroll
        for (int c = 0; c < 16; c++) {
            float4 v = *(const float4*)&h2[(size_t)i * C + c * 4];
            row[c * 4 + 0] = v.x; row[c * 4 + 1] = v.y;
            row[c * 4 + 2] = v.z; row[c * 4 + 3] = v.w;
        }
        float m = row[0];
        #pragma unroll
        for (int j = 1; j < 8; j++) m = fmaxf(m, row[j]);
        float ex[8], s = 0.f;
        #pragma unroll
        for (int j = 0; j < 8; j++) { ex[j] = __expf(row[j] - m); s += ex[j]; }
        float inv = 1.f / s;
        #pragma unroll
        for (int j = 0; j < 8; j += 4) {
            float4 v;
            v.x = ex[j + 0] * inv; v.y = ex[j + 1] * inv;
            v.z = ex[j + 2] * inv; v.w = ex[j + 3] * inv;
            *(float4*)&mid_out[(size_t)i * 8 + j] = v;
        }
        float z1[8];
        #pragma unroll
        for (int o = 0; o < 8; o++) z1[o] = b1s[o];
        for (int k = 0; k < 64; k++) {
            float a = row[k];
            #pragma unroll
            for (int o = 0; o < 8; o++) z1[o] += a * w1[k * 8 + o];
        }
        #pragma unroll
        for (int o = 0; o < 8; o++) z1[o] = fmaxf(z1[o], 0.f);
        float z2[2];
        #pragma unroll
        for (int p = 0; p < 2; p++) {
            float v = b2s[p];
            #pragma unroll
            for (int o = 0; o < 8; o++) v += z1[o] * w2[o * 2 + p];
            z2[p] = fmaxf(v, 0.f);
        }
        b = batch[i];
        u0 = __float_as_uint(z2[0]);
        u1 = __float_as_uint(z2[1]);
    }
    int b_lo = __shfl(b, 0), b_hi = __shfl(b, 63);
    if (b_lo == b_hi && b_lo >= 0) {
        #pragma unroll
        for (int off = 32; off > 0; off >>= 1) {
            unsigned int o0 = __shfl_xor(u0, off);
            unsigned int o1 = __shfl_xor(u1, off);
            u0 = u0 > o0 ? u0 : o0;
            u1 = u1 > o1 ? u1 : o1;
        }
        if ((t & 63) == 0) {
            atomicMax(&pool_s[b * 2 + 0], u0);
            atomicMax(&pool_s[b * 2 + 1], u1);
        }
    } else if (b >= 0) {
        atomicMax(&pool_s[b * 2 + 0], u0);
        atomicMax(&pool_s[b * 2 + 1], u1);
    }
    __syncthreads();
    if (t < N_GRAPHS * 2) {
        unsigned int v = pool_s[t];
        if (v) atomicMax(&pooled[t], v);
    }
}

__global__ void final_kernel(const unsigned int* __restrict__ pooled,
                             float* __restrict__ out) {
    int g = threadIdx.x;
    if (g < N_GRAPHS) {
        float v0 = __uint_as_float(pooled[g * 2 + 0]);
        float v1 = __uint_as_float(pooled[g * 2 + 1]);
        float m = fmaxf(v0, v1);
        float e0 = __expf(v0 - m), e1 = __expf(v1 - m);
        float s = e0 + e1;
        out[g * 2 + 0] = e0 / s;
        out[g * 2 + 1] = e1 / s;
    }
}

// ---------------- launch ----------------
extern "C" void kernel_launch(void* const* d_in, const int* in_sizes, int n_in,
                              void* d_out, int out_size, void* d_ws, size_t ws_size,
                              hipStream_t stream) {
    const float* x    = (const float*)d_in[0];
    const int*   ei   = (const int*)d_in[1];
    const int*   batch= (const int*)d_in[2];
    const float* W1r  = (const float*)d_in[3];
    const float* W1l  = (const float*)d_in[4];
    const float* b1   = (const float*)d_in[5];
    const float* W2r  = (const float*)d_in[6];
    const float* W2l  = (const float*)d_in[7];
    const float* b2   = (const float*)d_in[8];
    const float* fc1w = (const float*)d_in[9];
    const float* fc1b = (const float*)d_in[10];
    const float* fc2w = (const float*)d_in[11];
    const float* fc2b = (const float*)d_in[12];

    const int* src = ei;
    const int* dst = ei + N_EDGES;

    char* ws = (char*)d_ws;
    int*   bucketBase = (int*)(ws + OFF_BB);
    int*   epk        = (int*)(ws + OFF_EPK);
    float* agg        = (float*)(ws + OFF_AGG);   // also h2 (in-place)
    int*   hist_g     = (int*)(ws + OFF_AGG);     // alias: dead before agg is written
    float* h1         = (float*)(ws + OFF_H1);
    unsigned int* pooled = (unsigned int*)(ws + OFF_POOLED);

    float* mid_out = (float*)d_out;                       // 50000*8
    float* fin_out = (float*)d_out + (size_t)N_NODES * 8; // 64*2

    hipMemsetAsync(pooled, 0, N_GRAPHS * 2 * sizeof(unsigned int), stream);

    // coarse bucket sort of edges (replaces hist+scan+scatter CSR build)
    bucket_hist_kernel<<<NB, 256, 0, stream>>>(dst, hist_g);
    bucket_scan_kernel<<<1, 1024, 0, stream>>>(hist_g, bucketBase);
    bucket_scatter_kernel<<<NB, 256, 0, stream>>>(src, dst, hist_g, epk);

    const int GB = (N_NODES + 63) / 64;
    const int HB = (N_NODES + 255) / 256;

    // layer 1
    agg_kernel<<<NBKT, 1024, 0, stream>>>(x, epk, bucketBase, agg);
    gemm_kernel<<<GB, 256, 0, stream>>>(x, agg, W1r, W1l, b1, h1);
    // layer 2 (output written in-place over agg)
    agg_kernel<<<NBKT, 1024, 0, stream>>>(h1, epk, bucketBase, agg);
    gemm_kernel<<<GB, 256, 0, stream>>>(h1, agg, W2r, W2l, b2, agg);
    // head + pooling
    head_kernel<<<HB, 256, 0, stream>>>(agg, batch, fc1w, fc1b, fc2w, fc2b,
                                        mid_out, pooled);
    final_kernel<<<1, 64, 0, stream>>>(pooled, fin_out);
}

// Round 6
// 202.056 us; speedup vs baseline: 3.4045x; 3.4045x over previous
//
#include <hip/hip_runtime.h>

#define N_NODES 50000
#define N_EDGES 800000
#define C 64
#define N_GRAPHS 64

#define NBKT 256                          // coarse buckets (196 nodes each)
#define NPB 196
#define NBLK 256                          // pass-A grid
#define EPB (N_EDGES / NBLK)              // 3125 edges per block (exact)
#define FINE_CAP 8192                     // LDS staging capacity (32 KB)

// ---------------- workspace layout (bytes) ----------------
#define OFF_BB     0u          // bucketBase: (NBKT+1) ints
#define OFF_ROWPTR 1280u       // N_NODES+1 ints
#define OFF_ESRC   201472u     // N_EDGES ints (CSR src ids, sorted by dst)
#define OFF_EPK    3401472u    // N_EDGES ints packed (src | dst_local<<16)
#define OFF_H1     3401472u    // alias: h1 overwrites epk (dead after fine sort)
#define OFF_AGG    16201472u   // N_NODES*64 floats (hist_g aliases head; h2 in-place)
#define OFF_POOLED 29001472u   // N_GRAPHS*2 uints
// total ~29.0 MB

// ---------------- pass A1: per-block bucket histogram ----------------
__global__ __launch_bounds__(256) void bucket_hist_kernel(const int* __restrict__ dst,
                                                          int* __restrict__ hist_g) {
    __shared__ int h[NBKT];
    const int t = threadIdx.x;
    const int blk = blockIdx.x;
    h[t] = 0;
    __syncthreads();
    const int beg = blk * EPB;
    for (int i = beg + t; i < beg + EPB; i += 256)
        atomicAdd(&h[dst[i] / NPB], 1);
    __syncthreads();
    hist_g[t * NBLK + blk] = h[t];   // bucket-major for the scan
}

// ---------------- pass A2: exclusive scan of hist_g (65536) + bucket bases ----------------
__global__ __launch_bounds__(1024) void bucket_scan_kernel(int* __restrict__ hist_g,
                                                           int* __restrict__ bucketBase) {
    __shared__ int s[1024];
    const int t = threadIdx.x;
    const int PT = (NBKT * NBLK) / 1024;   // 64
    const int base = t * PT;
    int local = 0;
    for (int k = 0; k < PT; k++) local += hist_g[base + k];
    s[t] = local;
    __syncthreads();
    for (int off = 1; off < 1024; off <<= 1) {
        int v = 0;
        if (t >= off) v = s[t - off];
        __syncthreads();
        if (t >= off) s[t] += v;
        __syncthreads();
    }
    int run = s[t] - local;
    for (int k = 0; k < PT; k++) {
        int e = base + k;
        int v = hist_g[e];
        if ((e & (NBLK - 1)) == 0) bucketBase[e / NBLK] = run;
        hist_g[e] = run;
        run += v;
    }
    if (t == 0) bucketBase[NBKT] = N_EDGES;
}

// ---------------- pass A3: scatter packed edges into coarse bucket order ----------------
__global__ __launch_bounds__(256) void bucket_scatter_kernel(const int* __restrict__ src,
                                                             const int* __restrict__ dst,
                                                             const int* __restrict__ hist_g,
                                                             int* __restrict__ epk) {
    __shared__ int cur[NBKT];
    const int t = threadIdx.x;
    const int blk = blockIdx.x;
    cur[t] = hist_g[t * NBLK + blk];
    __syncthreads();
    const int beg = blk * EPB;
    for (int i = beg + t; i < beg + EPB; i += 256) {
        int d = dst[i];
        int b = d / NPB;
        int pos = atomicAdd(&cur[b], 1);
        epk[pos] = src[i] | ((d - b * NPB) << 16);   // src < 65536, local < 196
    }
}

// ---------------- pass B: fine sort within bucket -> CSR (esrc + rowptr) ----------------
__global__ __launch_bounds__(256) void fine_sort_kernel(const int* __restrict__ epk,
                                                        const int* __restrict__ bucketBase,
                                                        int* __restrict__ esrc,
                                                        int* __restrict__ rowptr) {
    __shared__ int cnt_s[NPB];
    __shared__ int s[256];
    __shared__ int staged[FINE_CAP];
    const int t = threadIdx.x;
    const int blk = blockIdx.x;
    const int base = bucketBase[blk], end = bucketBase[blk + 1];
    const int n = end - base;
    if (t < NPB) cnt_s[t] = 0;
    __syncthreads();
    for (int e = base + t; e < end; e += 256)
        atomicAdd(&cnt_s[((unsigned)epk[e]) >> 16], 1);
    __syncthreads();
    int v = (t < NPB) ? cnt_s[t] : 0;
    s[t] = v;
    __syncthreads();
    for (int off = 1; off < 256; off <<= 1) {
        int x = (t >= off) ? s[t - off] : 0;
        __syncthreads();
        if (t >= off) s[t] += x;
        __syncthreads();
    }
    int excl = s[t] - v;
    const int node0 = blk * NPB;
    if (t < NPB) {
        cnt_s[t] = excl;                           // local cursor
        if (node0 + t < N_NODES) rowptr[node0 + t] = base + excl;
    }
    if (blk == NBKT - 1 && t == 0) rowptr[N_NODES] = N_EDGES;
    __syncthreads();
    if (n <= FINE_CAP) {
        for (int e = base + t; e < end; e += 256) {
            int pk = epk[e];
            int pos = atomicAdd(&cnt_s[((unsigned)pk) >> 16], 1);
            staged[pos] = pk & 0xFFFF;
        }
        __syncthreads();
        for (int i = t; i < n; i += 256) esrc[base + i] = staged[i];  // coalesced
    } else {  // statistically unreachable fallback
        for (int e = base + t; e < end; e += 256) {
            int pk = epk[e];
            int pos = atomicAdd(&cnt_s[((unsigned)pk) >> 16], 1);
            esrc[base + pos] = pk & 0xFFFF;
        }
    }
}

// ---------------- aggregation: one wave per node, lane = feature ----------------
__global__ __launch_bounds__(256) void agg_kernel(const float* __restrict__ h,
                                                  const int* __restrict__ rowptr,
                                                  const int* __restrict__ esrc,
                                                  float* __restrict__ agg) {
    int wid = (blockIdx.x * blockDim.x + threadIdx.x) >> 6;
    int lane = threadIdx.x & 63;
    if (wid >= N_NODES) return;
    int beg = rowptr[wid], end = rowptr[wid + 1];
    float acc = 0.f;
    int e = beg;
    for (; e + 4 <= end; e += 4) {
        int j0 = esrc[e], j1 = esrc[e + 1], j2 = esrc[e + 2], j3 = esrc[e + 3];
        float a0 = h[(size_t)j0 * C + lane];
        float a1 = h[(size_t)j1 * C + lane];
        float a2 = h[(size_t)j2 * C + lane];
        float a3 = h[(size_t)j3 * C + lane];
        acc += a0; acc += a1; acc += a2; acc += a3;
    }
    for (; e < end; e++) acc += h[(size_t)esrc[e] * C + lane];
    agg[(size_t)wid * C + lane] = acc;
}

// ---------------- fused double-GEMM + bias + relu ----------------
// out = relu(A @ Wr + B @ Wl + bias). `out` may alias B (rows block-private,
// staged through LDS before write).
__global__ __launch_bounds__(256) void gemm_kernel(const float* __restrict__ A,
                                                   const float* __restrict__ B,
                                                   const float* __restrict__ Wr,
                                                   const float* __restrict__ Wl,
                                                   const float* __restrict__ bias,
                                                   float* out) {
    __shared__ float Wrs[64 * 64];
    __shared__ float Wls[64 * 64];
    __shared__ float As[64 * 65];
    __shared__ float Bs[64 * 65];
    const int t = threadIdx.x;
    const int row0 = blockIdx.x * 64;
    for (int i = t * 4; i < 4096; i += 1024) {
        *(float4*)&Wrs[i] = *(const float4*)&Wr[i];
        *(float4*)&Wls[i] = *(const float4*)&Wl[i];
    }
    const int r = t >> 2;
    const int q = t & 3;
    const int grow = row0 + r;
    if (grow < N_NODES) {
        #pragma unroll
        for (int c = 0; c < 4; c++) {
            *(float4*)&As[r * 65 + q * 16 + c * 4] =
                *(const float4*)&A[(size_t)grow * C + q * 16 + c * 4];
            *(float4*)&Bs[r * 65 + q * 16 + c * 4] =
                *(const float4*)&B[(size_t)grow * C + q * 16 + c * 4];
        }
    }
    __syncthreads();
    const int f0 = q * 16;
    float acc[16];
    #pragma unroll
    for (int ff = 0; ff < 16; ff++) acc[ff] = bias[f0 + ff];
    for (int k = 0; k < 64; k++) {
        float a = As[r * 65 + k];
        float b = Bs[r * 65 + k];
        #pragma unroll
        for (int ff = 0; ff < 16; ff++)
            acc[ff] += a * Wrs[k * 64 + f0 + ff] + b * Wls[k * 64 + f0 + ff];
    }
    if (grow < N_NODES) {
        #pragma unroll
        for (int ff = 0; ff < 16; ff += 4) {
            float4 v;
            v.x = fmaxf(acc[ff + 0], 0.f);
            v.y = fmaxf(acc[ff + 1], 0.f);
            v.z = fmaxf(acc[ff + 2], 0.f);
            v.w = fmaxf(acc[ff + 3], 0.f);
            *(float4*)&out[(size_t)grow * C + f0 + ff] = v;
        }
    }
}

// ---------------- head: mid softmax + fc1 + fc2 + segment_max ----------------
__global__ __launch_bounds__(256) void head_kernel(const float* __restrict__ h2,
                                                   const int* __restrict__ batch,
                                                   const float* __restrict__ fc1w,
                                                   const float* __restrict__ fc1b,
                                                   const float* __restrict__ fc2w,
                                                   const float* __restrict__ fc2b,
                                                   float* __restrict__ mid_out,
                                                   unsigned int* __restrict__ pooled) {
    __shared__ float w1[64 * 8];
    __shared__ float b1s[8];
    __shared__ float w2[16];
    __shared__ float b2s[2];
    __shared__ unsigned int pool_s[N_GRAPHS * 2];
    const int t = threadIdx.x;
    for (int i = t; i < 512; i += 256) w1[i] = fc1w[i];
    if (t < 8) b1s[t] = fc1b[t];
    if (t < 16) w2[t] = fc2w[t];
    if (t < 2) b2s[t] = fc2b[t];
    if (t < N_GRAPHS * 2) pool_s[t] = 0u;
    __syncthreads();
    const int i = blockIdx.x * 256 + t;
    int b = -1;
    unsigned int u0 = 0u, u1 = 0u;
    if (i < N_NODES) {
        float row[64];
        #pragma unroll
        for (int c = 0; c < 16; c++) {
            float4 v = *(const float4*)&h2[(size_t)i * C + c * 4];
            row[c * 4 + 0] = v.x; row[c * 4 + 1] = v.y;
            row[c * 4 + 2] = v.z; row[c * 4 + 3] = v.w;
        }
        float m = row[0];
        #pragma unroll
        for (int j = 1; j < 8; j++) m = fmaxf(m, row[j]);
        float ex[8], s = 0.f;
        #pragma unroll
        for (int j = 0; j < 8; j++) { ex[j] = __expf(row[j] - m); s += ex[j]; }
        float inv = 1.f / s;
        #pragma unroll
        for (int j = 0; j < 8; j += 4) {
            float4 v;
            v.x = ex[j + 0] * inv; v.y = ex[j + 1] * inv;
            v.z = ex[j + 2] * inv; v.w = ex[j + 3] * inv;
            *(float4*)&mid_out[(size_t)i * 8 + j] = v;
        }
        float z1[8];
        #pragma unroll
        for (int o = 0; o < 8; o++) z1[o] = b1s[o];
        for (int k = 0; k < 64; k++) {
            float a = row[k];
            #pragma unroll
            for (int o = 0; o < 8; o++) z1[o] += a * w1[k * 8 + o];
        }
        #pragma unroll
        for (int o = 0; o < 8; o++) z1[o] = fmaxf(z1[o], 0.f);
        float z2[2];
        #pragma unroll
        for (int p = 0; p < 2; p++) {
            float v = b2s[p];
            #pragma unroll
            for (int o = 0; o < 8; o++) v += z1[o] * w2[o * 2 + p];
            z2[p] = fmaxf(v, 0.f);
        }
        b = batch[i];
        u0 = __float_as_uint(z2[0]);
        u1 = __float_as_uint(z2[1]);
    }
    int b_lo = __shfl(b, 0), b_hi = __shfl(b, 63);
    if (b_lo == b_hi && b_lo >= 0) {
        #pragma unroll
        for (int off = 32; off > 0; off >>= 1) {
            unsigned int o0 = __shfl_xor(u0, off);
            unsigned int o1 = __shfl_xor(u1, off);
            u0 = u0 > o0 ? u0 : o0;
            u1 = u1 > o1 ? u1 : o1;
        }
        if ((t & 63) == 0) {
            atomicMax(&pool_s[b * 2 + 0], u0);
            atomicMax(&pool_s[b * 2 + 1], u1);
        }
    } else if (b >= 0) {
        atomicMax(&pool_s[b * 2 + 0], u0);
        atomicMax(&pool_s[b * 2 + 1], u1);
    }
    __syncthreads();
    if (t < N_GRAPHS * 2) {
        unsigned int v = pool_s[t];
        if (v) atomicMax(&pooled[t], v);
    }
}

__global__ void final_kernel(const unsigned int* __restrict__ pooled,
                             float* __restrict__ out) {
    int g = threadIdx.x;
    if (g < N_GRAPHS) {
        float v0 = __uint_as_float(pooled[g * 2 + 0]);
        float v1 = __uint_as_float(pooled[g * 2 + 1]);
        float m = fmaxf(v0, v1);
        float e0 = __expf(v0 - m), e1 = __expf(v1 - m);
        float s = e0 + e1;
        out[g * 2 + 0] = e0 / s;
        out[g * 2 + 1] = e1 / s;
    }
}

// ---------------- launch ----------------
extern "C" void kernel_launch(void* const* d_in, const int* in_sizes, int n_in,
                              void* d_out, int out_size, void* d_ws, size_t ws_size,
                              hipStream_t stream) {
    const float* x    = (const float*)d_in[0];
    const int*   ei   = (const int*)d_in[1];
    const int*   batch= (const int*)d_in[2];
    const float* W1r  = (const float*)d_in[3];
    const float* W1l  = (const float*)d_in[4];
    const float* b1   = (const float*)d_in[5];
    const float* W2r  = (const float*)d_in[6];
    const float* W2l  = (const float*)d_in[7];
    const float* b2   = (const float*)d_in[8];
    const float* fc1w = (const float*)d_in[9];
    const float* fc1b = (const float*)d_in[10];
    const float* fc2w = (const float*)d_in[11];
    const float* fc2b = (const float*)d_in[12];

    const int* src = ei;
    const int* dst = ei + N_EDGES;

    char* ws = (char*)d_ws;
    int*   bucketBase = (int*)(ws + OFF_BB);
    int*   rowptr     = (int*)(ws + OFF_ROWPTR);
    int*   esrc       = (int*)(ws + OFF_ESRC);
    int*   epk        = (int*)(ws + OFF_EPK);    // dead after fine_sort
    float* h1         = (float*)(ws + OFF_H1);   // alias of epk region
    float* agg        = (float*)(ws + OFF_AGG);  // also h2 (in-place)
    int*   hist_g     = (int*)(ws + OFF_AGG);    // alias: dead before agg is written
    unsigned int* pooled = (unsigned int*)(ws + OFF_POOLED);

    float* mid_out = (float*)d_out;                       // 50000*8
    float* fin_out = (float*)d_out + (size_t)N_NODES * 8; // 64*2

    hipMemsetAsync(pooled, 0, N_GRAPHS * 2 * sizeof(unsigned int), stream);

    // CSR build: coarse bucket sort + in-LDS fine sort
    bucket_hist_kernel<<<NBLK, 256, 0, stream>>>(dst, hist_g);
    bucket_scan_kernel<<<1, 1024, 0, stream>>>(hist_g, bucketBase);
    bucket_scatter_kernel<<<NBLK, 256, 0, stream>>>(src, dst, hist_g, epk);
    fine_sort_kernel<<<NBKT, 256, 0, stream>>>(epk, bucketBase, esrc, rowptr);

    const int AB = (N_NODES + 3) / 4;     // 4 waves (nodes) per block
    const int GB = (N_NODES + 63) / 64;
    const int HB = (N_NODES + 255) / 256;

    // layer 1
    agg_kernel<<<AB, 256, 0, stream>>>(x, rowptr, esrc, agg);
    gemm_kernel<<<GB, 256, 0, stream>>>(x, agg, W1r, W1l, b1, h1);
    // layer 2 (output written in-place over agg)
    agg_kernel<<<AB, 256, 0, stream>>>(h1, rowptr, esrc, agg);
    gemm_kernel<<<GB, 256, 0, stream>>>(h1, agg, W2r, W2l, b2, agg);
    // head + pooling
    head_kernel<<<HB, 256, 0, stream>>>(agg, batch, fc1w, fc1b, fc2w, fc2b,
                                        mid_out, pooled);
    final_kernel<<<1, 64, 0, stream>>>(pooled, fin_out);
}

// Round 8
// 193.775 us; speedup vs baseline: 3.5500x; 1.0427x over previous
//
#include <hip/hip_runtime.h>
#include <hip/hip_fp16.h>

typedef _Float16 f16_t;

#define N_NODES 50000
#define N_EDGES 800000
#define C 64
#define N_GRAPHS 64

#define NBKT 256                          // coarse buckets (196 nodes each)
#define NPB 196
#define NBLK 256                          // pass-A grid
#define EPB (N_EDGES / NBLK)              // 3125 edges per block (exact)
#define FINE_CAP 8192                     // LDS staging capacity (32 KB)

// ---------------- workspace layout (bytes) ----------------
#define OFF_BB     0u          // bucketBase: (NBKT+1) ints
#define OFF_ROWPTR 1280u       // N_NODES+1 ints
#define OFF_ESRC   201472u     // N_EDGES ints (CSR src ids, sorted by dst)
#define OFF_EPK    3401472u    // N_EDGES ints packed (dead after fine_sort)
#define OFF_XH     3401472u    // alias: x as fp16 (written after fine_sort)
#define OFF_H1H    9801472u    // h1 as fp16 (written by gemm1)
#define OFF_AGG    16201472u   // N_NODES*64 floats (hist_g aliases; h2 in-place)
#define OFF_POOLED 29001472u   // N_GRAPHS*2 uints
// total ~29.0 MB

__device__ __forceinline__ unsigned pack2h(float x, float y) {
    __half2 h = __floats2half2_rn(x, y);
    return *reinterpret_cast<unsigned*>(&h);
}

// ---------------- pass A1: per-block bucket histogram (+ zero pooled) ----------------
__global__ __launch_bounds__(256) void bucket_hist_kernel(const int* __restrict__ dst,
                                                          int* __restrict__ hist_g,
                                                          unsigned int* __restrict__ pooled) {
    __shared__ int h[NBKT];
    const int t = threadIdx.x;
    const int blk = blockIdx.x;
    if (blk == 0 && t < N_GRAPHS * 2) pooled[t] = 0u;   // replaces hipMemsetAsync
    h[t] = 0;
    __syncthreads();
    const int beg = blk * EPB;
    for (int i = beg + t; i < beg + EPB; i += 256)
        atomicAdd(&h[dst[i] / NPB], 1);
    __syncthreads();
    hist_g[t * NBLK + blk] = h[t];   // bucket-major for the scan
}

// ---------------- pass A2: exclusive scan of hist_g (65536) + bucket bases ----------------
__global__ __launch_bounds__(1024) void bucket_scan_kernel(int* __restrict__ hist_g,
                                                           int* __restrict__ bucketBase) {
    __shared__ int s[1024];
    const int t = threadIdx.x;
    const int PT = (NBKT * NBLK) / 1024;   // 64
    const int base = t * PT;
    int local = 0;
    for (int k = 0; k < PT; k++) local += hist_g[base + k];
    s[t] = local;
    __syncthreads();
    for (int off = 1; off < 1024; off <<= 1) {
        int v = 0;
        if (t >= off) v = s[t - off];
        __syncthreads();
        if (t >= off) s[t] += v;
        __syncthreads();
    }
    int run = s[t] - local;
    for (int k = 0; k < PT; k++) {
        int e = base + k;
        int v = hist_g[e];
        if ((e & (NBLK - 1)) == 0) bucketBase[e / NBLK] = run;
        hist_g[e] = run;
        run += v;
    }
    if (t == 0) bucketBase[NBKT] = N_EDGES;
}

// ---------------- pass A3: scatter packed edges into coarse bucket order ----------------
__global__ __launch_bounds__(256) void bucket_scatter_kernel(const int* __restrict__ src,
                                                             const int* __restrict__ dst,
                                                             const int* __restrict__ hist_g,
                                                             int* __restrict__ epk) {
    __shared__ int cur[NBKT];
    const int t = threadIdx.x;
    const int blk = blockIdx.x;
    cur[t] = hist_g[t * NBLK + blk];
    __syncthreads();
    const int beg = blk * EPB;
    for (int i = beg + t; i < beg + EPB; i += 256) {
        int d = dst[i];
        int b = d / NPB;
        int pos = atomicAdd(&cur[b], 1);
        epk[pos] = src[i] | ((d - b * NPB) << 16);   // src < 65536, local < 196
    }
}

// ---------------- pass B: fine sort within bucket -> CSR (esrc + rowptr) ----------------
__global__ __launch_bounds__(256) void fine_sort_kernel(const int* __restrict__ epk,
                                                        const int* __restrict__ bucketBase,
                                                        int* __restrict__ esrc,
                                                        int* __restrict__ rowptr) {
    __shared__ int cnt_s[NPB];
    __shared__ int s[256];
    __shared__ int staged[FINE_CAP];
    const int t = threadIdx.x;
    const int blk = blockIdx.x;
    const int base = bucketBase[blk], end = bucketBase[blk + 1];
    const int n = end - base;
    if (t < NPB) cnt_s[t] = 0;
    __syncthreads();
    for (int e = base + t; e < end; e += 256)
        atomicAdd(&cnt_s[((unsigned)epk[e]) >> 16], 1);
    __syncthreads();
    int v = (t < NPB) ? cnt_s[t] : 0;
    s[t] = v;
    __syncthreads();
    for (int off = 1; off < 256; off <<= 1) {
        int x = (t >= off) ? s[t - off] : 0;
        __syncthreads();
        if (t >= off) s[t] += x;
        __syncthreads();
    }
    int excl = s[t] - v;
    const int node0 = blk * NPB;
    if (t < NPB) {
        cnt_s[t] = excl;
        if (node0 + t < N_NODES) rowptr[node0 + t] = base + excl;
    }
    if (blk == NBKT - 1 && t == 0) rowptr[N_NODES] = N_EDGES;
    __syncthreads();
    if (n <= FINE_CAP) {
        for (int e = base + t; e < end; e += 256) {
            int pk = epk[e];
            int pos = atomicAdd(&cnt_s[((unsigned)pk) >> 16], 1);
            staged[pos] = pk & 0xFFFF;
        }
        __syncthreads();
        for (int i = t; i < n; i += 256) esrc[base + i] = staged[i];  // coalesced
    } else {
        for (int e = base + t; e < end; e += 256) {
            int pk = epk[e];
            int pos = atomicAdd(&cnt_s[((unsigned)pk) >> 16], 1);
            esrc[base + pos] = pk & 0xFFFF;
        }
    }
}

// ---------------- cast fp32 -> fp16 (8 elements per thread) ----------------
__global__ __launch_bounds__(256) void cast_kernel(const float* __restrict__ in,
                                                   f16_t* __restrict__ out) {
    const int i = blockIdx.x * 256 + threadIdx.x;
    const int n8 = N_NODES * C / 8;   // 400000
    if (i >= n8) return;
    const float4* p = (const float4*)(in + (size_t)i * 8);
    float4 a = p[0], b = p[1];
    uint4 w;
    w.x = pack2h(a.x, a.y);
    w.y = pack2h(a.z, a.w);
    w.z = pack2h(b.x, b.y);
    w.w = pack2h(b.z, b.w);
    *(uint4*)(out + (size_t)i * 8) = w;
}

// ---------------- aggregation: one wave per node, lane = feature, fp16 gather ----------------
__global__ __launch_bounds__(256) void agg_kernel(const f16_t* __restrict__ hh,
                                                  const int* __restrict__ rowptr,
                                                  const int* __restrict__ esrc,
                                                  float* __restrict__ agg) {
    int wid = (blockIdx.x * blockDim.x + threadIdx.x) >> 6;
    int lane = threadIdx.x & 63;
    if (wid >= N_NODES) return;
    int beg = rowptr[wid], end = rowptr[wid + 1];
    float acc = 0.f;
    int e = beg;
    for (; e + 4 <= end; e += 4) {
        int j0 = esrc[e], j1 = esrc[e + 1], j2 = esrc[e + 2], j3 = esrc[e + 3];
        float a0 = (float)hh[(size_t)j0 * C + lane];
        float a1 = (float)hh[(size_t)j1 * C + lane];
        float a2 = (float)hh[(size_t)j2 * C + lane];
        float a3 = (float)hh[(size_t)j3 * C + lane];
        acc += a0; acc += a1; acc += a2; acc += a3;
    }
    for (; e < end; e++) acc += (float)hh[(size_t)esrc[e] * C + lane];
    agg[(size_t)wid * C + lane] = acc;
}

// ---------------- fused double-GEMM + bias + relu (dual-precision I/O) ----------------
// out = relu(A @ Wr + B @ Wl + bias). A from A32 or Ah (fp16). Output to
// out32 and/or out16 (null-skipped, uniform branches). out32 may alias B.
__global__ __launch_bounds__(256) void gemm_kernel(const float* __restrict__ A32,
                                                   const f16_t* __restrict__ Ah,
                                                   const float* __restrict__ B,
                                                   const float* __restrict__ Wr,
                                                   const float* __restrict__ Wl,
                                                   const float* __restrict__ bias,
                                                   float* out32, f16_t* out16) {
    __shared__ float Wrs[64 * 64];
    __shared__ float Wls[64 * 64];
    __shared__ float As[64 * 65];
    __shared__ float Bs[64 * 65];
    const int t = threadIdx.x;
    const int row0 = blockIdx.x * 64;
    for (int i = t * 4; i < 4096; i += 1024) {
        *(float4*)&Wrs[i] = *(const float4*)&Wr[i];
        *(float4*)&Wls[i] = *(const float4*)&Wl[i];
    }
    const int r = t >> 2;
    const int q = t & 3;
    const int grow = row0 + r;
    if (grow < N_NODES) {
        if (Ah) {
            const unsigned* pa = (const unsigned*)&Ah[(size_t)grow * C + q * 16];
            #pragma unroll
            for (int c = 0; c < 8; c++) {
                unsigned w = pa[c];
                __half2 hh = *reinterpret_cast<__half2*>(&w);
                float2 ff = __half22float2(hh);
                As[r * 65 + q * 16 + 2 * c]     = ff.x;
                As[r * 65 + q * 16 + 2 * c + 1] = ff.y;
            }
        } else {
            #pragma unroll
            for (int c = 0; c < 4; c++)
                *(float4*)&As[r * 65 + q * 16 + c * 4] =
                    *(const float4*)&A32[(size_t)grow * C + q * 16 + c * 4];
        }
        #pragma unroll
        for (int c = 0; c < 4; c++)
            *(float4*)&Bs[r * 65 + q * 16 + c * 4] =
                *(const float4*)&B[(size_t)grow * C + q * 16 + c * 4];
    }
    __syncthreads();
    const int f0 = q * 16;
    float acc[16];
    #pragma unroll
    for (int ff = 0; ff < 16; ff++) acc[ff] = bias[f0 + ff];
    for (int k = 0; k < 64; k++) {
        float a = As[r * 65 + k];
        float b = Bs[r * 65 + k];
        #pragma unroll
        for (int ff = 0; ff < 16; ff++)
            acc[ff] += a * Wrs[k * 64 + f0 + ff] + b * Wls[k * 64 + f0 + ff];
    }
    if (grow < N_NODES) {
        #pragma unroll
        for (int ff = 0; ff < 16; ff++) acc[ff] = fmaxf(acc[ff], 0.f);
        if (out32) {
            #pragma unroll
            for (int ff = 0; ff < 16; ff += 4) {
                float4 v = {acc[ff], acc[ff + 1], acc[ff + 2], acc[ff + 3]};
                *(float4*)&out32[(size_t)grow * C + f0 + ff] = v;
            }
        }
        if (out16) {
            uint4 w0, w1;
            w0.x = pack2h(acc[0],  acc[1]);
            w0.y = pack2h(acc[2],  acc[3]);
            w0.z = pack2h(acc[4],  acc[5]);
            w0.w = pack2h(acc[6],  acc[7]);
            w1.x = pack2h(acc[8],  acc[9]);
            w1.y = pack2h(acc[10], acc[11]);
            w1.z = pack2h(acc[12], acc[13]);
            w1.w = pack2h(acc[14], acc[15]);
            *(uint4*)&out16[(size_t)grow * C + f0]     = w0;
            *(uint4*)&out16[(size_t)grow * C + f0 + 8] = w1;
        }
    }
}

// ---------------- head: mid softmax + fc1 + fc2 + segment_max ----------------
__global__ __launch_bounds__(256) void head_kernel(const float* __restrict__ h2,
                                                   const int* __restrict__ batch,
                                                   const float* __restrict__ fc1w,
                                                   const float* __restrict__ fc1b,
                                                   const float* __restrict__ fc2w,
                                                   const float* __restrict__ fc2b,
                                                   float* __restrict__ mid_out,
                                                   unsigned int* __restrict__ pooled) {
    __shared__ float w1[64 * 8];
    __shared__ float b1s[8];
    __shared__ float w2[16];
    __shared__ float b2s[2];
    __shared__ unsigned int pool_s[N_GRAPHS * 2];
    const int t = threadIdx.x;
    for (int i = t; i < 512; i += 256) w1[i] = fc1w[i];
    if (t < 8) b1s[t] = fc1b[t];
    if (t < 16) w2[t] = fc2w[t];
    if (t < 2) b2s[t] = fc2b[t];
    if (t < N_GRAPHS * 2) pool_s[t] = 0u;
    __syncthreads();
    const int i = blockIdx.x * 256 + t;
    int b = -1;
    unsigned int u0 = 0u, u1 = 0u;
    if (i < N_NODES) {
        float row[64];
        #pragma unroll
        for (int c = 0; c < 16; c++) {
            float4 v = *(const float4*)&h2[(size_t)i * C + c * 4];
            row[c * 4 + 0] = v.x; row[c * 4 + 1] = v.y;
            row[c * 4 + 2] = v.z; row[c * 4 + 3] = v.w;
        }
        float m = row[0];
        #pragma unroll
        for (int j = 1; j < 8; j++) m = fmaxf(m, row[j]);
        float ex[8], s = 0.f;
        #pragma unroll
        for (int j = 0; j < 8; j++) { ex[j] = __expf(row[j] - m); s += ex[j]; }
        float inv = 1.f / s;
        #pragma unroll
        for (int j = 0; j < 8; j += 4) {
            float4 v;
            v.x = ex[j + 0] * inv; v.y = ex[j + 1] * inv;
            v.z = ex[j + 2] * inv; v.w = ex[j + 3] * inv;
            *(float4*)&mid_out[(size_t)i * 8 + j] = v;
        }
        float z1[8];
        #pragma unroll
        for (int o = 0; o < 8; o++) z1[o] = b1s[o];
        for (int k = 0; k < 64; k++) {
            float a = row[k];
            #pragma unroll
            for (int o = 0; o < 8; o++) z1[o] += a * w1[k * 8 + o];
        }
        #pragma unroll
        for (int o = 0; o < 8; o++) z1[o] = fmaxf(z1[o], 0.f);
        float z2[2];
        #pragma unroll
        for (int p = 0; p < 2; p++) {
            float v = b2s[p];
            #pragma unroll
            for (int o = 0; o < 8; o++) v += z1[o] * w2[o * 2 + p];
            z2[p] = fmaxf(v, 0.f);
        }
        b = batch[i];
        u0 = __float_as_uint(z2[0]);
        u1 = __float_as_uint(z2[1]);
    }
    int b_lo = __shfl(b, 0), b_hi = __shfl(b, 63);
    if (b_lo == b_hi && b_lo >= 0) {
        #pragma unroll
        for (int off = 32; off > 0; off >>= 1) {
            unsigned int o0 = __shfl_xor(u0, off);
            unsigned int o1 = __shfl_xor(u1, off);
            u0 = u0 > o0 ? u0 : o0;
            u1 = u1 > o1 ? u1 : o1;
        }
        if ((t & 63) == 0) {
            atomicMax(&pool_s[b * 2 + 0], u0);
            atomicMax(&pool_s[b * 2 + 1], u1);
        }
    } else if (b >= 0) {
        atomicMax(&pool_s[b * 2 + 0], u0);
        atomicMax(&pool_s[b * 2 + 1], u1);
    }
    __syncthreads();
    if (t < N_GRAPHS * 2) {
        unsigned int v = pool_s[t];
        if (v) atomicMax(&pooled[t], v);
    }
}

__global__ void final_kernel(const unsigned int* __restrict__ pooled,
                             float* __restrict__ out) {
    int g = threadIdx.x;
    if (g < N_GRAPHS) {
        float v0 = __uint_as_float(pooled[g * 2 + 0]);
        float v1 = __uint_as_float(pooled[g * 2 + 1]);
        float m = fmaxf(v0, v1);
        float e0 = __expf(v0 - m), e1 = __expf(v1 - m);
        float s = e0 + e1;
        out[g * 2 + 0] = e0 / s;
        out[g * 2 + 1] = e1 / s;
    }
}

// ---------------- launch ----------------
extern "C" void kernel_launch(void* const* d_in, const int* in_sizes, int n_in,
                              void* d_out, int out_size, void* d_ws, size_t ws_size,
                              hipStream_t stream) {
    const float* x    = (const float*)d_in[0];
    const int*   ei   = (const int*)d_in[1];
    const int*   batch= (const int*)d_in[2];
    const float* W1r  = (const float*)d_in[3];
    const float* W1l  = (const float*)d_in[4];
    const float* b1   = (const float*)d_in[5];
    const float* W2r  = (const float*)d_in[6];
    const float* W2l  = (const float*)d_in[7];
    const float* b2   = (const float*)d_in[8];
    const float* fc1w = (const float*)d_in[9];
    const float* fc1b = (const float*)d_in[10];
    const float* fc2w = (const float*)d_in[11];
    const float* fc2b = (const float*)d_in[12];

    const int* src = ei;
    const int* dst = ei + N_EDGES;

    char* ws = (char*)d_ws;
    int*    bucketBase = (int*)(ws + OFF_BB);
    int*    rowptr     = (int*)(ws + OFF_ROWPTR);
    int*    esrc       = (int*)(ws + OFF_ESRC);
    int*    epk        = (int*)(ws + OFF_EPK);    // dead after fine_sort
    f16_t*  xh         = (f16_t*)(ws + OFF_XH);   // alias of epk region
    f16_t*  h1h        = (f16_t*)(ws + OFF_H1H);
    float*  agg        = (float*)(ws + OFF_AGG);  // also h2 (in-place)
    int*    hist_g     = (int*)(ws + OFF_AGG);    // alias: dead before agg written
    unsigned int* pooled = (unsigned int*)(ws + OFF_POOLED);

    float* mid_out = (float*)d_out;                       // 50000*8
    float* fin_out = (float*)d_out + (size_t)N_NODES * 8; // 64*2

    // CSR build: coarse bucket sort + in-LDS fine sort
    bucket_hist_kernel<<<NBLK, 256, 0, stream>>>(dst, hist_g, pooled);
    bucket_scan_kernel<<<1, 1024, 0, stream>>>(hist_g, bucketBase);
    bucket_scatter_kernel<<<NBLK, 256, 0, stream>>>(src, dst, hist_g, epk);
    fine_sort_kernel<<<NBKT, 256, 0, stream>>>(epk, bucketBase, esrc, rowptr);
    cast_kernel<<<(N_NODES * C / 8 + 255) / 256, 256, 0, stream>>>(x, xh);

    const int AB = (N_NODES + 3) / 4;     // 4 waves (nodes) per block
    const int GB = (N_NODES + 63) / 64;
    const int HB = (N_NODES + 255) / 256;

    // layer 1: agg over fp16 x; gemm reads fp32 x, emits h1 as fp16 only
    agg_kernel<<<AB, 256, 0, stream>>>(xh, rowptr, esrc, agg);
    gemm_kernel<<<GB, 256, 0, stream>>>(x, nullptr, agg, W1r, W1l, b1,
                                        nullptr, h1h);
    // layer 2: agg over fp16 h1; gemm reads fp16 A, writes h2 fp32 over agg
    agg_kernel<<<AB, 256, 0, stream>>>(h1h, rowptr, esrc, agg);
    gemm_kernel<<<GB, 256, 0, stream>>>(nullptr, h1h, agg, W2r, W2l, b2,
                                        agg, nullptr);
    // head + pooling
    head_kernel<<<HB, 256, 0, stream>>>(agg, batch, fc1w, fc1b, fc2w, fc2b,
                                        mid_out, pooled);
    final_kernel<<<1, 64, 0, stream>>>(pooled, fin_out);
}

// Round 9
// 145.432 us; speedup vs baseline: 4.7300x; 1.3324x over previous
//
#include <hip/hip_runtime.h>
#include <hip/hip_fp16.h>

typedef _Float16 f16_t;
typedef _Float16 f16x8 __attribute__((ext_vector_type(8)));
typedef float f32x4 __attribute__((ext_vector_type(4)));

#define N_NODES 50000
#define N_EDGES 800000
#define C 64
#define N_GRAPHS 64

#define NBKT 256                          // coarse buckets (196 nodes each)
#define NPB 196
#define NBLK 256                          // pass-A grid
#define EPB (N_EDGES / NBLK)              // 3125 edges per block (exact)
#define FINE_CAP 8192                     // LDS staging capacity (32 KB)

// ---------------- workspace layout (bytes; ws is ~256 MB per fill evidence) ----
#define OFF_BB     0u          // bucketBase: (NBKT+1) ints
#define OFF_ROWPTR 1280u       // N_NODES+1 ints
#define OFF_ESRC   201472u     // N_EDGES ints (CSR src ids, sorted by dst)
#define OFF_EPK    3401472u    // N_EDGES ints packed (dead after fine_sort)
#define OFF_XH     3401472u    // alias: x as fp16 (6.4 MB, written after fine_sort)
#define OFF_H1H    9801472u    // h1 fp16 (6.4 MB)
#define OFF_AGGH   16201472u   // agg fp16 (6.4 MB; hist_g aliases head of this)
#define OFF_H2     22601472u   // h2 fp32 (12.8 MB)
#define OFF_WT1    35401472u   // Wcat1^T fp16 (16 KB)
#define OFF_WT2    35417856u   // Wcat2^T fp16 (16 KB)
#define OFF_POOLED 35434240u   // N_GRAPHS*2 uints
// total ~35.4 MB

__device__ __forceinline__ unsigned pack2h(float x, float y) {
    __half2 h = __floats2half2_rn(x, y);
    return *reinterpret_cast<unsigned*>(&h);
}

// ---------------- pass A1: per-block bucket histogram (+ zero pooled) ----------------
__global__ __launch_bounds__(256) void bucket_hist_kernel(const int* __restrict__ dst,
                                                          int* __restrict__ hist_g,
                                                          unsigned int* __restrict__ pooled) {
    __shared__ int h[NBKT];
    const int t = threadIdx.x;
    const int blk = blockIdx.x;
    if (blk == 0 && t < N_GRAPHS * 2) pooled[t] = 0u;
    h[t] = 0;
    __syncthreads();
    const int beg = blk * EPB;
    for (int i = beg + t; i < beg + EPB; i += 256)
        atomicAdd(&h[dst[i] / NPB], 1);
    __syncthreads();
    hist_g[t * NBLK + blk] = h[t];   // bucket-major for the scan
}

// ---------------- pass A2: exclusive scan of hist_g (65536) + bucket bases ----------------
__global__ __launch_bounds__(1024) void bucket_scan_kernel(int* __restrict__ hist_g,
                                                           int* __restrict__ bucketBase) {
    __shared__ int s[1024];
    const int t = threadIdx.x;
    const int PT = (NBKT * NBLK) / 1024;   // 64
    const int base = t * PT;
    int local = 0;
    for (int k = 0; k < PT; k++) local += hist_g[base + k];
    s[t] = local;
    __syncthreads();
    for (int off = 1; off < 1024; off <<= 1) {
        int v = 0;
        if (t >= off) v = s[t - off];
        __syncthreads();
        if (t >= off) s[t] += v;
        __syncthreads();
    }
    int run = s[t] - local;
    for (int k = 0; k < PT; k++) {
        int e = base + k;
        int v = hist_g[e];
        if ((e & (NBLK - 1)) == 0) bucketBase[e / NBLK] = run;
        hist_g[e] = run;
        run += v;
    }
    if (t == 0) bucketBase[NBKT] = N_EDGES;
}

// ---------------- pass A3: scatter packed edges into coarse bucket order ----------------
__global__ __launch_bounds__(256) void bucket_scatter_kernel(const int* __restrict__ src,
                                                             const int* __restrict__ dst,
                                                             const int* __restrict__ hist_g,
                                                             int* __restrict__ epk) {
    __shared__ int cur[NBKT];
    const int t = threadIdx.x;
    const int blk = blockIdx.x;
    cur[t] = hist_g[t * NBLK + blk];
    __syncthreads();
    const int beg = blk * EPB;
    for (int i = beg + t; i < beg + EPB; i += 256) {
        int d = dst[i];
        int b = d / NPB;
        int pos = atomicAdd(&cur[b], 1);
        epk[pos] = src[i] | ((d - b * NPB) << 16);   // src < 65536, local < 196
    }
}

// ---------------- pass B: fine sort within bucket -> CSR (esrc + rowptr) ----------------
__global__ __launch_bounds__(256) void fine_sort_kernel(const int* __restrict__ epk,
                                                        const int* __restrict__ bucketBase,
                                                        int* __restrict__ esrc,
                                                        int* __restrict__ rowptr) {
    __shared__ int cnt_s[NPB];
    __shared__ int s[256];
    __shared__ int staged[FINE_CAP];
    const int t = threadIdx.x;
    const int blk = blockIdx.x;
    const int base = bucketBase[blk], end = bucketBase[blk + 1];
    const int n = end - base;
    if (t < NPB) cnt_s[t] = 0;
    __syncthreads();
    for (int e = base + t; e < end; e += 256)
        atomicAdd(&cnt_s[((unsigned)epk[e]) >> 16], 1);
    __syncthreads();
    int v = (t < NPB) ? cnt_s[t] : 0;
    s[t] = v;
    __syncthreads();
    for (int off = 1; off < 256; off <<= 1) {
        int x = (t >= off) ? s[t - off] : 0;
        __syncthreads();
        if (t >= off) s[t] += x;
        __syncthreads();
    }
    int excl = s[t] - v;
    const int node0 = blk * NPB;
    if (t < NPB) {
        cnt_s[t] = excl;
        if (node0 + t < N_NODES) rowptr[node0 + t] = base + excl;
    }
    if (blk == NBKT - 1 && t == 0) rowptr[N_NODES] = N_EDGES;
    __syncthreads();
    if (n <= FINE_CAP) {
        for (int e = base + t; e < end; e += 256) {
            int pk = epk[e];
            int pos = atomicAdd(&cnt_s[((unsigned)pk) >> 16], 1);
            staged[pos] = pk & 0xFFFF;
        }
        __syncthreads();
        for (int i = t; i < n; i += 256) esrc[base + i] = staged[i];  // coalesced
    } else {
        for (int e = base + t; e < end; e += 256) {
            int pk = epk[e];
            int pos = atomicAdd(&cnt_s[((unsigned)pk) >> 16], 1);
            esrc[base + pos] = pk & 0xFFFF;
        }
    }
}

// ---------------- cast fp32 -> fp16 (8 elements per thread) ----------------
__global__ __launch_bounds__(256) void cast_kernel(const float* __restrict__ in,
                                                   f16_t* __restrict__ out) {
    const int i = blockIdx.x * 256 + threadIdx.x;
    const int n8 = N_NODES * C / 8;   // 400000
    if (i >= n8) return;
    const float4* p = (const float4*)(in + (size_t)i * 8);
    float4 a = p[0], b = p[1];
    uint4 w;
    w.x = pack2h(a.x, a.y);
    w.y = pack2h(a.z, a.w);
    w.z = pack2h(b.x, b.y);
    w.w = pack2h(b.z, b.w);
    *(uint4*)(out + (size_t)i * 8) = w;
}

// ---------------- W transpose+cast: Wt[n][kk] = (kk<64 ? Wr[kk][n] : Wl[kk-64][n]) ----
__global__ __launch_bounds__(256) void wcast_kernel(const float* __restrict__ Wr,
                                                    const float* __restrict__ Wl,
                                                    f16_t* __restrict__ Wt) {
    __shared__ float w0[64 * 64];
    __shared__ float w1[64 * 64];
    const int t = threadIdx.x;
    for (int i = t * 4; i < 4096; i += 1024) {
        *(float4*)&w0[i] = *(const float4*)&Wr[i];
        *(float4*)&w1[i] = *(const float4*)&Wl[i];
    }
    __syncthreads();
    const int n = t >> 2, q = t & 3;
    for (int kk = q * 32; kk < q * 32 + 32; kk++) {
        float v = (kk < 64) ? w0[kk * 64 + n] : w1[(kk - 64) * 64 + n];
        Wt[n * 128 + kk] = (f16_t)v;   // 64B contiguous per thread
    }
}

// ---------------- aggregation: wave per node; half-wave edge pairing ----------------
// lanes 0-31: even-slot edges, lanes 32-63: odd-slot; lane j owns features 2j,2j+1.
__global__ __launch_bounds__(256) void agg_kernel(const f16_t* __restrict__ hh,
                                                  const int* __restrict__ rowptr,
                                                  const int* __restrict__ esrc,
                                                  f16_t* __restrict__ aggh) {
    const int wid = (blockIdx.x * 256 + threadIdx.x) >> 6;
    const int lane = threadIdx.x & 63;
    if (wid >= N_NODES) return;
    const int half = lane >> 5, j = lane & 31;
    const unsigned* hw = (const unsigned*)hh;   // 32 dwords per row
    int beg = rowptr[wid], end = rowptr[wid + 1];
    float sx = 0.f, sy = 0.f;
    int e = beg;
    for (; e + 8 <= end; e += 8) {              // 4 gathers cover 8 edges
        int i0 = esrc[e + 0 + half];
        int i1 = esrc[e + 2 + half];
        int i2 = esrc[e + 4 + half];
        int i3 = esrc[e + 6 + half];
        unsigned u0 = hw[(size_t)i0 * 32 + j];
        unsigned u1 = hw[(size_t)i1 * 32 + j];
        unsigned u2 = hw[(size_t)i2 * 32 + j];
        unsigned u3 = hw[(size_t)i3 * 32 + j];
        float2 f0 = __half22float2(*reinterpret_cast<__half2*>(&u0));
        float2 f1 = __half22float2(*reinterpret_cast<__half2*>(&u1));
        float2 f2 = __half22float2(*reinterpret_cast<__half2*>(&u2));
        float2 f3 = __half22float2(*reinterpret_cast<__half2*>(&u3));
        sx += f0.x + f1.x + f2.x + f3.x;
        sy += f0.y + f1.y + f2.y + f3.y;
    }
    for (; e < end; e += 2) {
        if (e + half < end) {
            unsigned u = hw[(size_t)esrc[e + half] * 32 + j];
            float2 f = __half22float2(*reinterpret_cast<__half2*>(&u));
            sx += f.x; sy += f.y;
        }
    }
    sx += __shfl_xor(sx, 32);
    sy += __shfl_xor(sy, 32);
    if (half == 0)
        ((unsigned*)aggh)[(size_t)wid * 32 + j] = pack2h(sx, sy);
}

// ---------------- MFMA GEMM: out = relu([A|agg] @ [Wr;Wl]^ + bias) ----------------
// A,agg fp16; Wt = Wcat^T fp16 (n-major, k=128); fp32 accumulation.
// LDS rows XOR-swizzled (byte ^= (row&7)<<4) to avoid stride-256B bank conflicts.
__global__ __launch_bounds__(256) void gemm_mfma_kernel(const f16_t* __restrict__ Ah,
                                                        const f16_t* __restrict__ Bh,
                                                        const f16_t* __restrict__ Wt,
                                                        const float* __restrict__ bias,
                                                        float* out32, f16_t* out16) {
    __shared__ f16_t Als[64 * 128];   // 16 KB, row = 256 B
    __shared__ f16_t Wls[64 * 128];   // 16 KB
    const int t = threadIdx.x;
    const int row0 = blockIdx.x * 64;
    const int r = t >> 2, q = t & 3;
    int gr = row0 + r; if (gr > N_NODES - 1) gr = N_NODES - 1;   // clamp (write guarded)
    const f16_t* srcA = (q < 2) ? &Ah[(size_t)gr * 64 + q * 32]
                                : &Bh[(size_t)gr * 64 + (q - 2) * 32];
    const f16_t* srcW = &Wt[r * 128 + q * 32];
    #pragma unroll
    for (int cc = 0; cc < 4; cc++) {
        const int c = q * 4 + cc;
        uint4 va = *(const uint4*)(srcA + cc * 8);
        uint4 vw = *(const uint4*)(srcW + cc * 8);
        *(uint4*)((char*)Als + r * 256 + ((c * 16) ^ ((r & 7) << 4))) = va;
        *(uint4*)((char*)Wls + r * 256 + ((c * 16) ^ ((r & 7) << 4))) = vw;
    }
    __syncthreads();
    const int w = t >> 6, l = t & 63;
    const int lr = l & 15;        // A-frag row / B-frag col / C col
    const int kh = l >> 4;        // 0..3
    const int arow = w * 16 + lr;
    f32x4 acc[4];
    #pragma unroll
    for (int nt = 0; nt < 4; nt++) {
        float b = bias[nt * 16 + lr];
        acc[nt] = (f32x4){b, b, b, b};
    }
    #pragma unroll
    for (int kt = 0; kt < 4; kt++) {
        const int kb = (kt * 32 + kh * 8) * 2;   // byte offset of lane's 8 fp16
        f16x8 a = *(const f16x8*)((const char*)Als + arow * 256 + (kb ^ ((arow & 7) << 4)));
        #pragma unroll
        for (int nt = 0; nt < 4; nt++) {
            const int n = nt * 16 + lr;
            f16x8 b = *(const f16x8*)((const char*)Wls + n * 256 + (kb ^ ((n & 7) << 4)));
            acc[nt] = __builtin_amdgcn_mfma_f32_16x16x32_f16(a, b, acc[nt], 0, 0, 0);
        }
    }
    // C layout: col = lane&15, row = (lane>>4)*4 + reg  [m89-verified]
    #pragma unroll
    for (int nt = 0; nt < 4; nt++) {
        const int col = nt * 16 + lr;
        #pragma unroll
        for (int rr = 0; rr < 4; rr++) {
            const int gm = row0 + w * 16 + kh * 4 + rr;
            if (gm < N_NODES) {
                float v = fmaxf(acc[nt][rr], 0.f);
                if (out32) out32[(size_t)gm * 64 + col] = v;
                if (out16) out16[(size_t)gm * 64 + col] = (f16_t)v;
            }
        }
    }
}

// ---------------- head: mid softmax + fc1 + fc2 + segment_max ----------------
__global__ __launch_bounds__(256) void head_kernel(const float* __restrict__ h2,
                                                   const int* __restrict__ batch,
                                                   const float* __restrict__ fc1w,
                                                   const float* __restrict__ fc1b,
                                                   const float* __restrict__ fc2w,
                                                   const float* __restrict__ fc2b,
                                                   float* __restrict__ mid_out,
                                                   unsigned int* __restrict__ pooled) {
    __shared__ float w1[64 * 8];
    __shared__ float b1s[8];
    __shared__ float w2[16];
    __shared__ float b2s[2];
    __shared__ unsigned int pool_s[N_GRAPHS * 2];
    const int t = threadIdx.x;
    for (int i = t; i < 512; i += 256) w1[i] = fc1w[i];
    if (t < 8) b1s[t] = fc1b[t];
    if (t < 16) w2[t] = fc2w[t];
    if (t < 2) b2s[t] = fc2b[t];
    if (t < N_GRAPHS * 2) pool_s[t] = 0u;
    __syncthreads();
    const int i = blockIdx.x * 256 + t;
    int b = -1;
    unsigned int u0 = 0u, u1 = 0u;
    if (i < N_NODES) {
        float row[64];
        #pragma unroll
        for (int c = 0; c < 16; c++) {
            float4 v = *(const float4*)&h2[(size_t)i * C + c * 4];
            row[c * 4 + 0] = v.x; row[c * 4 + 1] = v.y;
            row[c * 4 + 2] = v.z; row[c * 4 + 3] = v.w;
        }
        float m = row[0];
        #pragma unroll
        for (int j = 1; j < 8; j++) m = fmaxf(m, row[j]);
        float ex[8], s = 0.f;
        #pragma unroll
        for (int j = 0; j < 8; j++) { ex[j] = __expf(row[j] - m); s += ex[j]; }
        float inv = 1.f / s;
        #pragma unroll
        for (int j = 0; j < 8; j += 4) {
            float4 v;
            v.x = ex[j + 0] * inv; v.y = ex[j + 1] * inv;
            v.z = ex[j + 2] * inv; v.w = ex[j + 3] * inv;
            *(float4*)&mid_out[(size_t)i * 8 + j] = v;
        }
        float z1[8];
        #pragma unroll
        for (int o = 0; o < 8; o++) z1[o] = b1s[o];
        for (int k = 0; k < 64; k++) {
            float a = row[k];
            #pragma unroll
            for (int o = 0; o < 8; o++) z1[o] += a * w1[k * 8 + o];
        }
        #pragma unroll
        for (int o = 0; o < 8; o++) z1[o] = fmaxf(z1[o], 0.f);
        float z2[2];
        #pragma unroll
        for (int p = 0; p < 2; p++) {
            float v = b2s[p];
            #pragma unroll
            for (int o = 0; o < 8; o++) v += z1[o] * w2[o * 2 + p];
            z2[p] = fmaxf(v, 0.f);
        }
        b = batch[i];
        u0 = __float_as_uint(z2[0]);
        u1 = __float_as_uint(z2[1]);
    }
    int b_lo = __shfl(b, 0), b_hi = __shfl(b, 63);
    if (b_lo == b_hi && b_lo >= 0) {
        #pragma unroll
        for (int off = 32; off > 0; off >>= 1) {
            unsigned int o0 = __shfl_xor(u0, off);
            unsigned int o1 = __shfl_xor(u1, off);
            u0 = u0 > o0 ? u0 : o0;
            u1 = u1 > o1 ? u1 : o1;
        }
        if ((t & 63) == 0) {
            atomicMax(&pool_s[b * 2 + 0], u0);
            atomicMax(&pool_s[b * 2 + 1], u1);
        }
    } else if (b >= 0) {
        atomicMax(&pool_s[b * 2 + 0], u0);
        atomicMax(&pool_s[b * 2 + 1], u1);
    }
    __syncthreads();
    if (t < N_GRAPHS * 2) {
        unsigned int v = pool_s[t];
        if (v) atomicMax(&pooled[t], v);
    }
}

__global__ void final_kernel(const unsigned int* __restrict__ pooled,
                             float* __restrict__ out) {
    int g = threadIdx.x;
    if (g < N_GRAPHS) {
        float v0 = __uint_as_float(pooled[g * 2 + 0]);
        float v1 = __uint_as_float(pooled[g * 2 + 1]);
        float m = fmaxf(v0, v1);
        float e0 = __expf(v0 - m), e1 = __expf(v1 - m);
        float s = e0 + e1;
        out[g * 2 + 0] = e0 / s;
        out[g * 2 + 1] = e1 / s;
    }
}

// ---------------- launch ----------------
extern "C" void kernel_launch(void* const* d_in, const int* in_sizes, int n_in,
                              void* d_out, int out_size, void* d_ws, size_t ws_size,
                              hipStream_t stream) {
    const float* x    = (const float*)d_in[0];
    const int*   ei   = (const int*)d_in[1];
    const int*   batch= (const int*)d_in[2];
    const float* W1r  = (const float*)d_in[3];
    const float* W1l  = (const float*)d_in[4];
    const float* b1   = (const float*)d_in[5];
    const float* W2r  = (const float*)d_in[6];
    const float* W2l  = (const float*)d_in[7];
    const float* b2   = (const float*)d_in[8];
    const float* fc1w = (const float*)d_in[9];
    const float* fc1b = (const float*)d_in[10];
    const float* fc2w = (const float*)d_in[11];
    const float* fc2b = (const float*)d_in[12];

    const int* src = ei;
    const int* dst = ei + N_EDGES;

    char* ws = (char*)d_ws;
    int*    bucketBase = (int*)(ws + OFF_BB);
    int*    rowptr     = (int*)(ws + OFF_ROWPTR);
    int*    esrc       = (int*)(ws + OFF_ESRC);
    int*    epk        = (int*)(ws + OFF_EPK);    // dead after fine_sort
    f16_t*  xh         = (f16_t*)(ws + OFF_XH);   // alias of epk region
    f16_t*  h1h        = (f16_t*)(ws + OFF_H1H);
    f16_t*  aggh       = (f16_t*)(ws + OFF_AGGH);
    int*    hist_g     = (int*)(ws + OFF_AGGH);   // alias: dead before aggh written
    float*  h2         = (float*)(ws + OFF_H2);
    f16_t*  Wt1        = (f16_t*)(ws + OFF_WT1);
    f16_t*  Wt2        = (f16_t*)(ws + OFF_WT2);
    unsigned int* pooled = (unsigned int*)(ws + OFF_POOLED);

    float* mid_out = (float*)d_out;                       // 50000*8
    float* fin_out = (float*)d_out + (size_t)N_NODES * 8; // 64*2

    // CSR build: coarse bucket sort + in-LDS fine sort
    bucket_hist_kernel<<<NBLK, 256, 0, stream>>>(dst, hist_g, pooled);
    bucket_scan_kernel<<<1, 1024, 0, stream>>>(hist_g, bucketBase);
    bucket_scatter_kernel<<<NBLK, 256, 0, stream>>>(src, dst, hist_g, epk);
    fine_sort_kernel<<<NBKT, 256, 0, stream>>>(epk, bucketBase, esrc, rowptr);
    cast_kernel<<<(N_NODES * C / 8 + 255) / 256, 256, 0, stream>>>(x, xh);
    wcast_kernel<<<1, 256, 0, stream>>>(W1r, W1l, Wt1);
    wcast_kernel<<<1, 256, 0, stream>>>(W2r, W2l, Wt2);

    const int AB = (N_NODES + 3) / 4;     // 4 waves (nodes) per block
    const int GB = (N_NODES + 63) / 64;   // 782
    const int HB = (N_NODES + 255) / 256;

    // layer 1: agg(xh) -> aggh; MFMA gemm -> h1h (fp16)
    agg_kernel<<<AB, 256, 0, stream>>>(xh, rowptr, esrc, aggh);
    gemm_mfma_kernel<<<GB, 256, 0, stream>>>(xh, aggh, Wt1, b1, nullptr, h1h);
    // layer 2: agg(h1h) -> aggh; MFMA gemm -> h2 (fp32)
    agg_kernel<<<AB, 256, 0, stream>>>(h1h, rowptr, esrc, aggh);
    gemm_mfma_kernel<<<GB, 256, 0, stream>>>(h1h, aggh, Wt2, b2, h2, nullptr);
    // head + pooling
    head_kernel<<<HB, 256, 0, stream>>>(h2, batch, fc1w, fc1b, fc2w, fc2b,
                                        mid_out, pooled);
    final_kernel<<<1, 64, 0, stream>>>(pooled, fin_out);
}

// Round 10
// 141.846 us; speedup vs baseline: 4.8496x; 1.0253x over previous
//
#include <hip/hip_runtime.h>
#include <hip/hip_fp16.h>

typedef _Float16 f16_t;
typedef _Float16 f16x8 __attribute__((ext_vector_type(8)));
typedef float f32x4 __attribute__((ext_vector_type(4)));

#define N_NODES 50000
#define N_EDGES 800000
#define C 64
#define N_GRAPHS 64

#define NBKT 256                          // coarse buckets (196 nodes each)
#define NPB 196
#define NBLK 256                          // pass-A grid
#define EPB (N_EDGES / NBLK)              // 3125 edges per block (exact)
#define FINE_CAP 8192                     // LDS staging capacity (32 KB)
#define CAST_BLKS 1563                    // ceil(400000/256)

// ---------------- workspace layout (bytes; ws ~256 MB) ----------------
#define OFF_BB     0u          // bucketBase: (NBKT+1) ints
#define OFF_ROWPTR 1280u       // N_NODES+1 ints
#define OFF_ESRC   201472u     // N_EDGES ints (CSR src ids, sorted by dst)
#define OFF_EPK    3401472u    // N_EDGES ints packed (dead after fine_sort)
#define OFF_XH     6601472u    // x as fp16 (6.4 MB) -- NOT aliased with epk now
#define OFF_H1H    13001472u   // h1 fp16 (6.4 MB)
#define OFF_AGGH   19401472u   // agg fp16 (6.4 MB; hist_g aliases head of this)
#define OFF_WT1    25801472u   // Wcat1^T fp16 (16 KB)
#define OFF_WT2    25817856u   // Wcat2^T fp16 (16 KB)
#define OFF_POOLED 25834240u   // N_GRAPHS*2 uints
#define OFF_DONE   25834752u   // completion counter
// total ~25.8 MB

__device__ __forceinline__ unsigned pack2h(float x, float y) {
    __half2 h = __floats2half2_rn(x, y);
    return *reinterpret_cast<unsigned*>(&h);
}

// ---------------- prep: bucket histogram (blocks 0..255) + x->fp16 cast ----------------
__global__ __launch_bounds__(256) void prep_kernel(const int* __restrict__ dst,
                                                   int* __restrict__ hist_g,
                                                   const float* __restrict__ x,
                                                   f16_t* __restrict__ xh,
                                                   unsigned int* __restrict__ pooled,
                                                   unsigned int* __restrict__ done_cnt) {
    const int blk = blockIdx.x;
    const int t = threadIdx.x;
    if (blk < NBLK) {
        __shared__ int h[NBKT];
        if (blk == 0) {
            if (t < N_GRAPHS * 2) pooled[t] = 0u;
            if (t == 0) *done_cnt = 0u;
        }
        h[t] = 0;
        __syncthreads();
        const int beg = blk * EPB;
        for (int i = beg + t; i < beg + EPB; i += 256)
            atomicAdd(&h[dst[i] / NPB], 1);
        __syncthreads();
        hist_g[t * NBLK + blk] = h[t];   // bucket-major for the scan
    } else {
        const int i = (blk - NBLK) * 256 + t;
        const int n8 = N_NODES * C / 8;   // 400000
        if (i < n8) {
            const float4* p = (const float4*)(x + (size_t)i * 8);
            float4 a = p[0], b = p[1];
            uint4 w;
            w.x = pack2h(a.x, a.y);
            w.y = pack2h(a.z, a.w);
            w.z = pack2h(b.x, b.y);
            w.w = pack2h(b.z, b.w);
            *(uint4*)(xh + (size_t)i * 8) = w;
        }
    }
}

// ---------------- pass A2: exclusive scan of hist_g (65536) + bucket bases ----------------
__global__ __launch_bounds__(1024) void bucket_scan_kernel(int* __restrict__ hist_g,
                                                           int* __restrict__ bucketBase) {
    __shared__ int s[1024];
    const int t = threadIdx.x;
    const int PT = (NBKT * NBLK) / 1024;   // 64
    const int base = t * PT;
    int local = 0;
    for (int k = 0; k < PT; k++) local += hist_g[base + k];
    s[t] = local;
    __syncthreads();
    for (int off = 1; off < 1024; off <<= 1) {
        int v = 0;
        if (t >= off) v = s[t - off];
        __syncthreads();
        if (t >= off) s[t] += v;
        __syncthreads();
    }
    int run = s[t] - local;
    for (int k = 0; k < PT; k++) {
        int e = base + k;
        int v = hist_g[e];
        if ((e & (NBLK - 1)) == 0) bucketBase[e / NBLK] = run;
        hist_g[e] = run;
        run += v;
    }
    if (t == 0) bucketBase[NBKT] = N_EDGES;
}

// ---------------- pass A3: scatter packed edges into coarse bucket order ----------------
__global__ __launch_bounds__(256) void bucket_scatter_kernel(const int* __restrict__ src,
                                                             const int* __restrict__ dst,
                                                             const int* __restrict__ hist_g,
                                                             int* __restrict__ epk) {
    __shared__ int cur[NBKT];
    const int t = threadIdx.x;
    const int blk = blockIdx.x;
    cur[t] = hist_g[t * NBLK + blk];
    __syncthreads();
    const int beg = blk * EPB;
    for (int i = beg + t; i < beg + EPB; i += 256) {
        int d = dst[i];
        int b = d / NPB;
        int pos = atomicAdd(&cur[b], 1);
        epk[pos] = src[i] | ((d - b * NPB) << 16);   // src < 65536, local < 196
    }
}

// ---------------- pass B: fine sort within bucket -> CSR (esrc + rowptr) ----------------
__global__ __launch_bounds__(256) void fine_sort_kernel(const int* __restrict__ epk,
                                                        const int* __restrict__ bucketBase,
                                                        int* __restrict__ esrc,
                                                        int* __restrict__ rowptr) {
    __shared__ int cnt_s[NPB];
    __shared__ int s[256];
    __shared__ int staged[FINE_CAP];
    const int t = threadIdx.x;
    const int blk = blockIdx.x;
    const int base = bucketBase[blk], end = bucketBase[blk + 1];
    const int n = end - base;
    if (t < NPB) cnt_s[t] = 0;
    __syncthreads();
    for (int e = base + t; e < end; e += 256)
        atomicAdd(&cnt_s[((unsigned)epk[e]) >> 16], 1);
    __syncthreads();
    int v = (t < NPB) ? cnt_s[t] : 0;
    s[t] = v;
    __syncthreads();
    for (int off = 1; off < 256; off <<= 1) {
        int x = (t >= off) ? s[t - off] : 0;
        __syncthreads();
        if (t >= off) s[t] += x;
        __syncthreads();
    }
    int excl = s[t] - v;
    const int node0 = blk * NPB;
    if (t < NPB) {
        cnt_s[t] = excl;
        if (node0 + t < N_NODES) rowptr[node0 + t] = base + excl;
    }
    if (blk == NBKT - 1 && t == 0) rowptr[N_NODES] = N_EDGES;
    __syncthreads();
    if (n <= FINE_CAP) {
        for (int e = base + t; e < end; e += 256) {
            int pk = epk[e];
            int pos = atomicAdd(&cnt_s[((unsigned)pk) >> 16], 1);
            staged[pos] = pk & 0xFFFF;
        }
        __syncthreads();
        for (int i = t; i < n; i += 256) esrc[base + i] = staged[i];  // coalesced
    } else {
        for (int e = base + t; e < end; e += 256) {
            int pk = epk[e];
            int pos = atomicAdd(&cnt_s[((unsigned)pk) >> 16], 1);
            esrc[base + pos] = pk & 0xFFFF;
        }
    }
}

// ---------------- W transpose+cast x2: Wt[n][kk] = (kk<64 ? Wr : Wl)[kk%64][n] ----------
__global__ __launch_bounds__(256) void wcast2_kernel(const float* __restrict__ W1r,
                                                     const float* __restrict__ W1l,
                                                     f16_t* __restrict__ Wt1,
                                                     const float* __restrict__ W2r,
                                                     const float* __restrict__ W2l,
                                                     f16_t* __restrict__ Wt2) {
    const float* Wr = blockIdx.x ? W2r : W1r;
    const float* Wl = blockIdx.x ? W2l : W1l;
    f16_t* Wt = blockIdx.x ? Wt2 : Wt1;
    __shared__ float w0[64 * 64];
    __shared__ float w1[64 * 64];
    const int t = threadIdx.x;
    for (int i = t * 4; i < 4096; i += 1024) {
        *(float4*)&w0[i] = *(const float4*)&Wr[i];
        *(float4*)&w1[i] = *(const float4*)&Wl[i];
    }
    __syncthreads();
    const int n = t >> 2, q = t & 3;
    for (int kk = q * 32; kk < q * 32 + 32; kk++) {
        float v = (kk < 64) ? w0[kk * 64 + n] : w1[(kk - 64) * 64 + n];
        Wt[n * 128 + kk] = (f16_t)v;
    }
}

// ---------------- aggregation: wave per node; 16 lanes x 8B per row, 4 edges/load ------
__global__ __launch_bounds__(256) void agg_kernel(const f16_t* __restrict__ hh,
                                                  const int* __restrict__ rowptr,
                                                  const int* __restrict__ esrc,
                                                  f16_t* __restrict__ aggh) {
    const int wid = (blockIdx.x * 256 + threadIdx.x) >> 6;
    const int lane = threadIdx.x & 63;
    if (wid >= N_NODES) return;
    const int slot = lane >> 4;          // edge slot 0..3
    const int j = lane & 15;             // 8-byte chunk of the 128B row
    const uint2* hw = (const uint2*)hh;  // 16 chunks per row
    int beg = rowptr[wid], end = rowptr[wid + 1];
    float s0 = 0.f, s1 = 0.f, s2 = 0.f, s3 = 0.f;
    int e = beg;
    for (; e + 16 <= end; e += 16) {     // 4 independent loads cover 16 edges
        int i0 = esrc[e + slot];
        int i1 = esrc[e + 4 + slot];
        int i2 = esrc[e + 8 + slot];
        int i3 = esrc[e + 12 + slot];
        uint2 u0 = hw[(size_t)i0 * 16 + j];
        uint2 u1 = hw[(size_t)i1 * 16 + j];
        uint2 u2 = hw[(size_t)i2 * 16 + j];
        uint2 u3 = hw[(size_t)i3 * 16 + j];
        float2 a, b;
        a = __half22float2(*(__half2*)&u0.x); b = __half22float2(*(__half2*)&u0.y);
        s0 += a.x; s1 += a.y; s2 += b.x; s3 += b.y;
        a = __half22float2(*(__half2*)&u1.x); b = __half22float2(*(__half2*)&u1.y);
        s0 += a.x; s1 += a.y; s2 += b.x; s3 += b.y;
        a = __half22float2(*(__half2*)&u2.x); b = __half22float2(*(__half2*)&u2.y);
        s0 += a.x; s1 += a.y; s2 += b.x; s3 += b.y;
        a = __half22float2(*(__half2*)&u3.x); b = __half22float2(*(__half2*)&u3.y);
        s0 += a.x; s1 += a.y; s2 += b.x; s3 += b.y;
    }
    for (; e + 4 <= end; e += 4) {
        int i = esrc[e + slot];
        uint2 u = hw[(size_t)i * 16 + j];
        float2 a = __half22float2(*(__half2*)&u.x);
        float2 b = __half22float2(*(__half2*)&u.y);
        s0 += a.x; s1 += a.y; s2 += b.x; s3 += b.y;
    }
    int rem = end - e;
    if (slot < rem) {
        int i = esrc[e + slot];
        uint2 u = hw[(size_t)i * 16 + j];
        float2 a = __half22float2(*(__half2*)&u.x);
        float2 b = __half22float2(*(__half2*)&u.y);
        s0 += a.x; s1 += a.y; s2 += b.x; s3 += b.y;
    }
    s0 += __shfl_xor(s0, 16); s1 += __shfl_xor(s1, 16);
    s2 += __shfl_xor(s2, 16); s3 += __shfl_xor(s3, 16);
    s0 += __shfl_xor(s0, 32); s1 += __shfl_xor(s1, 32);
    s2 += __shfl_xor(s2, 32); s3 += __shfl_xor(s3, 32);
    if (slot == 0) {
        uint2 o;
        o.x = pack2h(s0, s1);
        o.y = pack2h(s2, s3);
        ((uint2*)aggh)[(size_t)wid * 16 + j] = o;
    }
}

// ---------------- MFMA GEMM (layer 1): h1 = relu([A|agg] @ Wcat^T + b) -> fp16 --------
__global__ __launch_bounds__(256) void gemm_mfma_kernel(const f16_t* __restrict__ Ah,
                                                        const f16_t* __restrict__ Bh,
                                                        const f16_t* __restrict__ Wt,
                                                        const float* __restrict__ bias,
                                                        f16_t* __restrict__ out16) {
    __shared__ f16_t Als[64 * 128];
    __shared__ f16_t Wls[64 * 128];
    const int t = threadIdx.x;
    const int row0 = blockIdx.x * 64;
    const int r = t >> 2, q = t & 3;
    int gr = row0 + r; if (gr > N_NODES - 1) gr = N_NODES - 1;
    const f16_t* srcA = (q < 2) ? &Ah[(size_t)gr * 64 + q * 32]
                                : &Bh[(size_t)gr * 64 + (q - 2) * 32];
    const f16_t* srcW = &Wt[r * 128 + q * 32];
    #pragma unroll
    for (int cc = 0; cc < 4; cc++) {
        const int c = q * 4 + cc;
        uint4 va = *(const uint4*)(srcA + cc * 8);
        uint4 vw = *(const uint4*)(srcW + cc * 8);
        *(uint4*)((char*)Als + r * 256 + ((c * 16) ^ ((r & 7) << 4))) = va;
        *(uint4*)((char*)Wls + r * 256 + ((c * 16) ^ ((r & 7) << 4))) = vw;
    }
    __syncthreads();
    const int w = t >> 6, l = t & 63;
    const int lr = l & 15, kh = l >> 4;
    const int arow = w * 16 + lr;
    f32x4 acc[4];
    #pragma unroll
    for (int nt = 0; nt < 4; nt++) {
        float b = bias[nt * 16 + lr];
        acc[nt] = (f32x4){b, b, b, b};
    }
    #pragma unroll
    for (int kt = 0; kt < 4; kt++) {
        const int kb = (kt * 32 + kh * 8) * 2;
        f16x8 a = *(const f16x8*)((const char*)Als + arow * 256 + (kb ^ ((arow & 7) << 4)));
        #pragma unroll
        for (int nt = 0; nt < 4; nt++) {
            const int n = nt * 16 + lr;
            f16x8 b = *(const f16x8*)((const char*)Wls + n * 256 + (kb ^ ((n & 7) << 4)));
            acc[nt] = __builtin_amdgcn_mfma_f32_16x16x32_f16(a, b, acc[nt], 0, 0, 0);
        }
    }
    #pragma unroll
    for (int nt = 0; nt < 4; nt++) {
        const int col = nt * 16 + lr;
        #pragma unroll
        for (int rr = 0; rr < 4; rr++) {
            const int gm = row0 + w * 16 + kh * 4 + rr;
            if (gm < N_NODES)
                out16[(size_t)gm * 64 + col] = (f16_t)fmaxf(acc[nt][rr], 0.f);
        }
    }
}

// ---------------- MFMA GEMM (layer 2) fused with head + pooling + final ----------------
__global__ __launch_bounds__(256) void gemm2_head_kernel(
        const f16_t* __restrict__ Ah, const f16_t* __restrict__ Bh,
        const f16_t* __restrict__ Wt, const float* __restrict__ bias,
        const int* __restrict__ batch,
        const float* __restrict__ fc1w, const float* __restrict__ fc1b,
        const float* __restrict__ fc2w, const float* __restrict__ fc2b,
        float* __restrict__ mid_out, unsigned int* __restrict__ pooled,
        unsigned int* __restrict__ done_cnt, float* __restrict__ fin_out) {
    __shared__ f16_t Als[64 * 128];
    __shared__ f16_t Wls[64 * 128];
    __shared__ float tile[64 * 65];
    __shared__ float w1s[512];
    __shared__ float z1s[64 * 9];
    __shared__ float b1s[8];
    __shared__ float w2s[16];
    __shared__ float b2s[2];
    __shared__ unsigned int pool_s[N_GRAPHS * 2];
    __shared__ unsigned int amLast;
    __shared__ float fin[N_GRAPHS * 2];
    const int t = threadIdx.x;
    const int row0 = blockIdx.x * 64;
    const int r = t >> 2, q = t & 3;
    int gr = row0 + r; if (gr > N_NODES - 1) gr = N_NODES - 1;
    const f16_t* srcA = (q < 2) ? &Ah[(size_t)gr * 64 + q * 32]
                                : &Bh[(size_t)gr * 64 + (q - 2) * 32];
    const f16_t* srcW = &Wt[r * 128 + q * 32];
    #pragma unroll
    for (int cc = 0; cc < 4; cc++) {
        const int c = q * 4 + cc;
        uint4 va = *(const uint4*)(srcA + cc * 8);
        uint4 vw = *(const uint4*)(srcW + cc * 8);
        *(uint4*)((char*)Als + r * 256 + ((c * 16) ^ ((r & 7) << 4))) = va;
        *(uint4*)((char*)Wls + r * 256 + ((c * 16) ^ ((r & 7) << 4))) = vw;
    }
    for (int i = t; i < 512; i += 256) w1s[i] = fc1w[i];
    if (t < 8) b1s[t] = fc1b[t];
    if (t < 16) w2s[t] = fc2w[t];
    if (t < 2) b2s[t] = fc2b[t];
    if (t < N_GRAPHS * 2) pool_s[t] = 0u;
    __syncthreads();
    const int w = t >> 6, l = t & 63;
    const int lr = l & 15, kh = l >> 4;
    const int arow = w * 16 + lr;
    f32x4 acc[4];
    #pragma unroll
    for (int nt = 0; nt < 4; nt++) {
        float b = bias[nt * 16 + lr];
        acc[nt] = (f32x4){b, b, b, b};
    }
    #pragma unroll
    for (int kt = 0; kt < 4; kt++) {
        const int kb = (kt * 32 + kh * 8) * 2;
        f16x8 a = *(const f16x8*)((const char*)Als + arow * 256 + (kb ^ ((arow & 7) << 4)));
        #pragma unroll
        for (int nt = 0; nt < 4; nt++) {
            const int n = nt * 16 + lr;
            f16x8 b = *(const f16x8*)((const char*)Wls + n * 256 + (kb ^ ((n & 7) << 4)));
            acc[nt] = __builtin_amdgcn_mfma_f32_16x16x32_f16(a, b, acc[nt], 0, 0, 0);
        }
    }
    // h2 tile -> LDS (relu applied)
    #pragma unroll
    for (int nt = 0; nt < 4; nt++) {
        const int col = nt * 16 + lr;
        #pragma unroll
        for (int rr = 0; rr < 4; rr++)
            tile[(w * 16 + kh * 4 + rr) * 65 + col] = fmaxf(acc[nt][rr], 0.f);
    }
    __syncthreads();
    // head: row = t&63; 4 threads per row each compute 2 of the 8 fc1 outputs
    const int row = t & 63, qq = t >> 6;
    const int gm = row0 + row;
    const bool valid = gm < N_NODES;
    {
        float z0 = b1s[2 * qq], z1v = b1s[2 * qq + 1];
        for (int k = 0; k < 64; k++) {
            float a = tile[row * 65 + k];
            z0  += a * w1s[k * 8 + 2 * qq];
            z1v += a * w1s[k * 8 + 2 * qq + 1];
        }
        z1s[row * 9 + 2 * qq]     = fmaxf(z0, 0.f);
        z1s[row * 9 + 2 * qq + 1] = fmaxf(z1v, 0.f);
    }
    if (qq == 0 && valid) {   // mid softmax over cols 0..7 (wave 0, uniform)
        float rv[8];
        #pragma unroll
        for (int c = 0; c < 8; c++) rv[c] = tile[row * 65 + c];
        float m = rv[0];
        #pragma unroll
        for (int c = 1; c < 8; c++) m = fmaxf(m, rv[c]);
        float ex[8], s = 0.f;
        #pragma unroll
        for (int c = 0; c < 8; c++) { ex[c] = __expf(rv[c] - m); s += ex[c]; }
        float inv = 1.f / s;
        float4 v0 = {ex[0] * inv, ex[1] * inv, ex[2] * inv, ex[3] * inv};
        float4 v1 = {ex[4] * inv, ex[5] * inv, ex[6] * inv, ex[7] * inv};
        *(float4*)&mid_out[(size_t)gm * 8]     = v0;
        *(float4*)&mid_out[(size_t)gm * 8 + 4] = v1;
    }
    __syncthreads();
    if (qq == 0 && valid) {   // fc2 + LDS pool
        float z20 = b2s[0], z21 = b2s[1];
        #pragma unroll
        for (int o = 0; o < 8; o++) {
            float z = z1s[row * 9 + o];
            z20 += z * w2s[o * 2];
            z21 += z * w2s[o * 2 + 1];
        }
        z20 = fmaxf(z20, 0.f);
        z21 = fmaxf(z21, 0.f);
        int b = batch[gm];
        atomicMax(&pool_s[b * 2 + 0], __float_as_uint(z20));
        atomicMax(&pool_s[b * 2 + 1], __float_as_uint(z21));
    }
    __syncthreads();
    if (t < N_GRAPHS * 2) {
        unsigned int v = pool_s[t];
        if (v) atomicMax(&pooled[t], v);
    }
    __syncthreads();
    if (t == 0) {
        __threadfence();
        unsigned int prev = atomicAdd(done_cnt, 1u);
        amLast = (prev == gridDim.x - 1) ? 1u : 0u;
    }
    __syncthreads();
    if (amLast) {   // block-uniform: last block computes the 64-graph softmax
        if (t < N_GRAPHS * 2) fin[t] = __uint_as_float(atomicMax(&pooled[t], 0u));
        __syncthreads();
        if (t < N_GRAPHS) {
            float v0 = fin[2 * t], v1 = fin[2 * t + 1];
            float m = fmaxf(v0, v1);
            float e0 = __expf(v0 - m), e1 = __expf(v1 - m);
            float s = e0 + e1;
            fin_out[2 * t]     = e0 / s;
            fin_out[2 * t + 1] = e1 / s;
        }
    }
}

// ---------------- launch ----------------
extern "C" void kernel_launch(void* const* d_in, const int* in_sizes, int n_in,
                              void* d_out, int out_size, void* d_ws, size_t ws_size,
                              hipStream_t stream) {
    const float* x    = (const float*)d_in[0];
    const int*   ei   = (const int*)d_in[1];
    const int*   batch= (const int*)d_in[2];
    const float* W1r  = (const float*)d_in[3];
    const float* W1l  = (const float*)d_in[4];
    const float* b1   = (const float*)d_in[5];
    const float* W2r  = (const float*)d_in[6];
    const float* W2l  = (const float*)d_in[7];
    const float* b2   = (const float*)d_in[8];
    const float* fc1w = (const float*)d_in[9];
    const float* fc1b = (const float*)d_in[10];
    const float* fc2w = (const float*)d_in[11];
    const float* fc2b = (const float*)d_in[12];

    const int* src = ei;
    const int* dst = ei + N_EDGES;

    char* ws = (char*)d_ws;
    int*    bucketBase = (int*)(ws + OFF_BB);
    int*    rowptr     = (int*)(ws + OFF_ROWPTR);
    int*    esrc       = (int*)(ws + OFF_ESRC);
    int*    epk        = (int*)(ws + OFF_EPK);
    f16_t*  xh         = (f16_t*)(ws + OFF_XH);
    f16_t*  h1h        = (f16_t*)(ws + OFF_H1H);
    f16_t*  aggh       = (f16_t*)(ws + OFF_AGGH);
    int*    hist_g     = (int*)(ws + OFF_AGGH);   // alias: dead before aggh written
    f16_t*  Wt1        = (f16_t*)(ws + OFF_WT1);
    f16_t*  Wt2        = (f16_t*)(ws + OFF_WT2);
    unsigned int* pooled   = (unsigned int*)(ws + OFF_POOLED);
    unsigned int* done_cnt = (unsigned int*)(ws + OFF_DONE);

    float* mid_out = (float*)d_out;                       // 50000*8
    float* fin_out = (float*)d_out + (size_t)N_NODES * 8; // 64*2

    // build + cast (one kernel), scan, scatter, fine sort, weight prep
    prep_kernel<<<NBLK + CAST_BLKS, 256, 0, stream>>>(dst, hist_g, x, xh,
                                                      pooled, done_cnt);
    bucket_scan_kernel<<<1, 1024, 0, stream>>>(hist_g, bucketBase);
    bucket_scatter_kernel<<<NBLK, 256, 0, stream>>>(src, dst, hist_g, epk);
    fine_sort_kernel<<<NBKT, 256, 0, stream>>>(epk, bucketBase, esrc, rowptr);
    wcast2_kernel<<<2, 256, 0, stream>>>(W1r, W1l, Wt1, W2r, W2l, Wt2);

    const int AB = (N_NODES + 3) / 4;     // 4 waves (nodes) per block
    const int GB = (N_NODES + 63) / 64;   // 782

    // layer 1
    agg_kernel<<<AB, 256, 0, stream>>>(xh, rowptr, esrc, aggh);
    gemm_mfma_kernel<<<GB, 256, 0, stream>>>(xh, aggh, Wt1, b1, h1h);
    // layer 2 + head + pooling + final (fused)
    agg_kernel<<<AB, 256, 0, stream>>>(h1h, rowptr, esrc, aggh);
    gemm2_head_kernel<<<GB, 256, 0, stream>>>(h1h, aggh, Wt2, b2, batch,
                                              fc1w, fc1b, fc2w, fc2b,
                                              mid_out, pooled, done_cnt, fin_out);
}

// Round 11
// 114.397 us; speedup vs baseline: 6.0133x; 1.2399x over previous
//
#include <hip/hip_runtime.h>
#include <hip/hip_fp16.h>

typedef _Float16 f16_t;
typedef _Float16 f16x8 __attribute__((ext_vector_type(8)));
typedef float f32x4 __attribute__((ext_vector_type(4)));

#define N_NODES 50000
#define N_EDGES 800000
#define C 64
#define N_GRAPHS 64

#define NBKT 256                   // coarse buckets (196 nodes each)
#define NPB 196
#define BKT_CAP 4096               // slots per bucket (mean 3125 + 17 sigma)
#define HS_BLOCKS 256              // hist+scatter grid
#define HS_EPB (N_EDGES / HS_BLOCKS)   // 3125 (exact)
#define CAST_BLKS 1563             // ceil(400000/256)
#define CUR_STRIDE 16              // pad cursors to one 64B line each

// ---------------- workspace layout (bytes; ws ~256 MB) ----------------
#define OFF_CUR    0u          // 256 cursors, padded x16 ints (16 KB)
#define OFF_POOLED 16384u      // N_GRAPHS*2 uints
#define OFF_DONE   16896u      // completion counter
#define OFF_ROWS   17152u      // N_NODES int2 {beg,end} (400 KB)
#define OFF_ESRC   417280u     // NBKT*BKT_CAP ints (4 MB), padded CSR
#define OFF_EPK    4611584u    // NBKT*BKT_CAP ints (4 MB)
#define OFF_XH     8805888u    // x fp16 (6.4 MB)
#define OFF_H1H    15205888u   // h1 fp16 (6.4 MB)
#define OFF_AGGH   21605888u   // agg fp16 (6.4 MB)
#define OFF_WT1    28005888u   // Wcat1^T fp16 (16 KB)
#define OFF_WT2    28022272u   // Wcat2^T fp16 (16 KB)
// total ~28.0 MB

__device__ __forceinline__ unsigned pack2h(float x, float y) {
    __half2 h = __floats2half2_rn(x, y);
    return *reinterpret_cast<unsigned*>(&h);
}

// ---------------- k0: init (block 0) + x->fp16 cast + W transpose/cast ----------------
__global__ __launch_bounds__(256) void init_cast_wcast_kernel(
        const float* __restrict__ x, f16_t* __restrict__ xh,
        const float* __restrict__ W1r, const float* __restrict__ W1l, f16_t* __restrict__ Wt1,
        const float* __restrict__ W2r, const float* __restrict__ W2l, f16_t* __restrict__ Wt2,
        int* __restrict__ cur, unsigned int* __restrict__ pooled,
        unsigned int* __restrict__ done_cnt) {
    __shared__ float w0[64 * 64];
    __shared__ float w1[64 * 64];
    const int blk = blockIdx.x;
    const int t = threadIdx.x;
    if (blk < CAST_BLKS) {
        if (blk == 0) {   // init (no other block touches these until next kernel)
            #pragma unroll
            for (int k = 0; k < CUR_STRIDE; k++) cur[k * 256 + t] = 0;
            if (t < N_GRAPHS * 2) pooled[t] = 0u;
            if (t == 0) *done_cnt = 0u;
        }
        const int i = blk * 256 + t;
        if (i < N_NODES * C / 8) {
            const float4* p = (const float4*)(x + (size_t)i * 8);
            float4 a = p[0], b = p[1];
            uint4 w;
            w.x = pack2h(a.x, a.y);
            w.y = pack2h(a.z, a.w);
            w.z = pack2h(b.x, b.y);
            w.w = pack2h(b.z, b.w);
            *(uint4*)(xh + (size_t)i * 8) = w;
        }
    } else {
        const int which = blk - CAST_BLKS;   // 0 or 1
        const float* Wr = which ? W2r : W1r;
        const float* Wl = which ? W2l : W1l;
        f16_t* Wt = which ? Wt2 : Wt1;
        for (int i = t * 4; i < 4096; i += 1024) {
            *(float4*)&w0[i] = *(const float4*)&Wr[i];
            *(float4*)&w1[i] = *(const float4*)&Wl[i];
        }
        __syncthreads();
        const int n = t >> 2, q = t & 3;
        for (int kk = q * 32; kk < q * 32 + 32; kk++) {
            float v = (kk < 64) ? w0[kk * 64 + n] : w1[(kk - 64) * 64 + n];
            Wt[n * 128 + kk] = (f16_t)v;
        }
    }
}

// ---------------- k1: fused hist + reserve + scatter (padded buckets) ----------------
__global__ __launch_bounds__(256) void hist_scatter_kernel(const int* __restrict__ src,
                                                           const int* __restrict__ dst,
                                                           int* __restrict__ cur,
                                                           int* __restrict__ epk) {
    __shared__ int h[NBKT];
    __shared__ int base_s[NBKT];
    const int t = threadIdx.x;
    const int blk = blockIdx.x;
    h[t] = 0;
    __syncthreads();
    const int beg = blk * HS_EPB;
    for (int i = beg + t; i < beg + HS_EPB; i += 256)
        atomicAdd(&h[dst[i] / NPB], 1);
    __syncthreads();
    {   // thread t reserves bucket t's range (padded-line global cursor)
        int hv = h[t];
        int old = hv ? atomicAdd(&cur[t * CUR_STRIDE], hv) : 0;
        base_s[t] = t * BKT_CAP + old;
        h[t] = 0;   // reuse as local cursor
    }
    __syncthreads();
    for (int i = beg + t; i < beg + HS_EPB; i += 256) {
        int d = dst[i];
        int b = d / NPB;
        int off = atomicAdd(&h[b], 1);
        int pos = base_s[b] + off;
        if (pos < (b + 1) * BKT_CAP)   // statistically unreachable guard
            epk[pos] = src[i] | ((d - b * NPB) << 16);
    }
}

// ---------------- k2: fine sort within bucket -> padded CSR (esrc + rows) ----------------
__global__ __launch_bounds__(256) void fine_sort_kernel(const int* __restrict__ epk,
                                                        const int* __restrict__ cur,
                                                        int* __restrict__ esrc,
                                                        int2* __restrict__ rows) {
    __shared__ int cnt_s[NPB];
    __shared__ int s[256];
    __shared__ int staged[BKT_CAP];
    const int t = threadIdx.x;
    const int blk = blockIdx.x;
    const int base = blk * BKT_CAP;
    int n = cur[blk * CUR_STRIDE];
    if (n > BKT_CAP) n = BKT_CAP;
    if (t < NPB) cnt_s[t] = 0;
    __syncthreads();
    for (int e = t; e < n; e += 256)
        atomicAdd(&cnt_s[((unsigned)epk[base + e]) >> 16], 1);
    __syncthreads();
    int v = (t < NPB) ? cnt_s[t] : 0;
    s[t] = v;
    __syncthreads();
    for (int off = 1; off < 256; off <<= 1) {
        int x = (t >= off) ? s[t - off] : 0;
        __syncthreads();
        if (t >= off) s[t] += x;
        __syncthreads();
    }
    int excl = s[t] - v;
    const int node = blk * NPB + t;
    if (t < NPB) {
        cnt_s[t] = excl;
        if (node < N_NODES) {
            int2 be; be.x = base + excl; be.y = base + excl + v;
            rows[node] = be;
        }
    }
    __syncthreads();
    for (int e = t; e < n; e += 256) {
        int pk = epk[base + e];
        int pos = atomicAdd(&cnt_s[((unsigned)pk) >> 16], 1);
        staged[pos] = pk & 0xFFFF;
    }
    __syncthreads();
    for (int i = t; i < n; i += 256) esrc[base + i] = staged[i];  // coalesced
}

// ---------------- aggregation: wave per node; 16 lanes x 8B per row, 4 edges/load ------
__global__ __launch_bounds__(256) void agg_kernel(const f16_t* __restrict__ hh,
                                                  const int2* __restrict__ rows,
                                                  const int* __restrict__ esrc,
                                                  f16_t* __restrict__ aggh) {
    const int wid = (blockIdx.x * 256 + threadIdx.x) >> 6;
    const int lane = threadIdx.x & 63;
    if (wid >= N_NODES) return;
    const int slot = lane >> 4;          // edge slot 0..3
    const int j = lane & 15;             // 8-byte chunk of the 128B row
    const uint2* hw = (const uint2*)hh;  // 16 chunks per row
    int2 be = rows[wid];
    int beg = be.x, end = be.y;
    float s0 = 0.f, s1 = 0.f, s2 = 0.f, s3 = 0.f;
    int e = beg;
    for (; e + 16 <= end; e += 16) {     // 4 independent loads cover 16 edges
        int i0 = esrc[e + slot];
        int i1 = esrc[e + 4 + slot];
        int i2 = esrc[e + 8 + slot];
        int i3 = esrc[e + 12 + slot];
        uint2 u0 = hw[(size_t)i0 * 16 + j];
        uint2 u1 = hw[(size_t)i1 * 16 + j];
        uint2 u2 = hw[(size_t)i2 * 16 + j];
        uint2 u3 = hw[(size_t)i3 * 16 + j];
        float2 a, b;
        a = __half22float2(*(__half2*)&u0.x); b = __half22float2(*(__half2*)&u0.y);
        s0 += a.x; s1 += a.y; s2 += b.x; s3 += b.y;
        a = __half22float2(*(__half2*)&u1.x); b = __half22float2(*(__half2*)&u1.y);
        s0 += a.x; s1 += a.y; s2 += b.x; s3 += b.y;
        a = __half22float2(*(__half2*)&u2.x); b = __half22float2(*(__half2*)&u2.y);
        s0 += a.x; s1 += a.y; s2 += b.x; s3 += b.y;
        a = __half22float2(*(__half2*)&u3.x); b = __half22float2(*(__half2*)&u3.y);
        s0 += a.x; s1 += a.y; s2 += b.x; s3 += b.y;
    }
    for (; e + 4 <= end; e += 4) {
        int i = esrc[e + slot];
        uint2 u = hw[(size_t)i * 16 + j];
        float2 a = __half22float2(*(__half2*)&u.x);
        float2 b = __half22float2(*(__half2*)&u.y);
        s0 += a.x; s1 += a.y; s2 += b.x; s3 += b.y;
    }
    int rem = end - e;
    if (slot < rem) {
        int i = esrc[e + slot];
        uint2 u = hw[(size_t)i * 16 + j];
        float2 a = __half22float2(*(__half2*)&u.x);
        float2 b = __half22float2(*(__half2*)&u.y);
        s0 += a.x; s1 += a.y; s2 += b.x; s3 += b.y;
    }
    s0 += __shfl_xor(s0, 16); s1 += __shfl_xor(s1, 16);
    s2 += __shfl_xor(s2, 16); s3 += __shfl_xor(s3, 16);
    s0 += __shfl_xor(s0, 32); s1 += __shfl_xor(s1, 32);
    s2 += __shfl_xor(s2, 32); s3 += __shfl_xor(s3, 32);
    if (slot == 0) {
        uint2 o;
        o.x = pack2h(s0, s1);
        o.y = pack2h(s2, s3);
        ((uint2*)aggh)[(size_t)wid * 16 + j] = o;
    }
}

// ---------------- MFMA GEMM (layer 1): h1 = relu([A|agg] @ Wcat^T + b) -> fp16 --------
__global__ __launch_bounds__(256) void gemm_mfma_kernel(const f16_t* __restrict__ Ah,
                                                        const f16_t* __restrict__ Bh,
                                                        const f16_t* __restrict__ Wt,
                                                        const float* __restrict__ bias,
                                                        f16_t* __restrict__ out16) {
    __shared__ f16_t Als[64 * 128];
    __shared__ f16_t Wls[64 * 128];
    const int t = threadIdx.x;
    const int row0 = blockIdx.x * 64;
    const int r = t >> 2, q = t & 3;
    int gr = row0 + r; if (gr > N_NODES - 1) gr = N_NODES - 1;
    const f16_t* srcA = (q < 2) ? &Ah[(size_t)gr * 64 + q * 32]
                                : &Bh[(size_t)gr * 64 + (q - 2) * 32];
    const f16_t* srcW = &Wt[r * 128 + q * 32];
    #pragma unroll
    for (int cc = 0; cc < 4; cc++) {
        const int c = q * 4 + cc;
        uint4 va = *(const uint4*)(srcA + cc * 8);
        uint4 vw = *(const uint4*)(srcW + cc * 8);
        *(uint4*)((char*)Als + r * 256 + ((c * 16) ^ ((r & 7) << 4))) = va;
        *(uint4*)((char*)Wls + r * 256 + ((c * 16) ^ ((r & 7) << 4))) = vw;
    }
    __syncthreads();
    const int w = t >> 6, l = t & 63;
    const int lr = l & 15, kh = l >> 4;
    const int arow = w * 16 + lr;
    f32x4 acc[4];
    #pragma unroll
    for (int nt = 0; nt < 4; nt++) {
        float b = bias[nt * 16 + lr];
        acc[nt] = (f32x4){b, b, b, b};
    }
    #pragma unroll
    for (int kt = 0; kt < 4; kt++) {
        const int kb = (kt * 32 + kh * 8) * 2;
        f16x8 a = *(const f16x8*)((const char*)Als + arow * 256 + (kb ^ ((arow & 7) << 4)));
        #pragma unroll
        for (int nt = 0; nt < 4; nt++) {
            const int n = nt * 16 + lr;
            f16x8 b = *(const f16x8*)((const char*)Wls + n * 256 + (kb ^ ((n & 7) << 4)));
            acc[nt] = __builtin_amdgcn_mfma_f32_16x16x32_f16(a, b, acc[nt], 0, 0, 0);
        }
    }
    #pragma unroll
    for (int nt = 0; nt < 4; nt++) {
        const int col = nt * 16 + lr;
        #pragma unroll
        for (int rr = 0; rr < 4; rr++) {
            const int gm = row0 + w * 16 + kh * 4 + rr;
            if (gm < N_NODES)
                out16[(size_t)gm * 64 + col] = (f16_t)fmaxf(acc[nt][rr], 0.f);
        }
    }
}

// ---------------- MFMA GEMM (layer 2) fused with head + pooling + final ----------------
__global__ __launch_bounds__(256) void gemm2_head_kernel(
        const f16_t* __restrict__ Ah, const f16_t* __restrict__ Bh,
        const f16_t* __restrict__ Wt, const float* __restrict__ bias,
        const int* __restrict__ batch,
        const float* __restrict__ fc1w, const float* __restrict__ fc1b,
        const float* __restrict__ fc2w, const float* __restrict__ fc2b,
        float* __restrict__ mid_out, unsigned int* __restrict__ pooled,
        unsigned int* __restrict__ done_cnt, float* __restrict__ fin_out) {
    __shared__ f16_t Als[64 * 128];
    __shared__ f16_t Wls[64 * 128];
    __shared__ float tile[64 * 65];
    __shared__ float w1s[512];
    __shared__ float z1s[64 * 9];
    __shared__ float b1s[8];
    __shared__ float w2s[16];
    __shared__ float b2s[2];
    __shared__ unsigned int pool_s[N_GRAPHS * 2];
    __shared__ unsigned int amLast;
    __shared__ float fin[N_GRAPHS * 2];
    const int t = threadIdx.x;
    const int row0 = blockIdx.x * 64;
    const int r = t >> 2, q = t & 3;
    int gr = row0 + r; if (gr > N_NODES - 1) gr = N_NODES - 1;
    const f16_t* srcA = (q < 2) ? &Ah[(size_t)gr * 64 + q * 32]
                                : &Bh[(size_t)gr * 64 + (q - 2) * 32];
    const f16_t* srcW = &Wt[r * 128 + q * 32];
    #pragma unroll
    for (int cc = 0; cc < 4; cc++) {
        const int c = q * 4 + cc;
        uint4 va = *(const uint4*)(srcA + cc * 8);
        uint4 vw = *(const uint4*)(srcW + cc * 8);
        *(uint4*)((char*)Als + r * 256 + ((c * 16) ^ ((r & 7) << 4))) = va;
        *(uint4*)((char*)Wls + r * 256 + ((c * 16) ^ ((r & 7) << 4))) = vw;
    }
    for (int i = t; i < 512; i += 256) w1s[i] = fc1w[i];
    if (t < 8) b1s[t] = fc1b[t];
    if (t < 16) w2s[t] = fc2w[t];
    if (t < 2) b2s[t] = fc2b[t];
    if (t < N_GRAPHS * 2) pool_s[t] = 0u;
    __syncthreads();
    const int w = t >> 6, l = t & 63;
    const int lr = l & 15, kh = l >> 4;
    const int arow = w * 16 + lr;
    f32x4 acc[4];
    #pragma unroll
    for (int nt = 0; nt < 4; nt++) {
        float b = bias[nt * 16 + lr];
        acc[nt] = (f32x4){b, b, b, b};
    }
    #pragma unroll
    for (int kt = 0; kt < 4; kt++) {
        const int kb = (kt * 32 + kh * 8) * 2;
        f16x8 a = *(const f16x8*)((const char*)Als + arow * 256 + (kb ^ ((arow & 7) << 4)));
        #pragma unroll
        for (int nt = 0; nt < 4; nt++) {
            const int n = nt * 16 + lr;
            f16x8 b = *(const f16x8*)((const char*)Wls + n * 256 + (kb ^ ((n & 7) << 4)));
            acc[nt] = __builtin_amdgcn_mfma_f32_16x16x32_f16(a, b, acc[nt], 0, 0, 0);
        }
    }
    #pragma unroll
    for (int nt = 0; nt < 4; nt++) {
        const int col = nt * 16 + lr;
        #pragma unroll
        for (int rr = 0; rr < 4; rr++)
            tile[(w * 16 + kh * 4 + rr) * 65 + col] = fmaxf(acc[nt][rr], 0.f);
    }
    __syncthreads();
    const int row = t & 63, qq = t >> 6;
    const int gm = row0 + row;
    const bool valid = gm < N_NODES;
    {
        float z0 = b1s[2 * qq], z1v = b1s[2 * qq + 1];
        for (int k = 0; k < 64; k++) {
            float a = tile[row * 65 + k];
            z0  += a * w1s[k * 8 + 2 * qq];
            z1v += a * w1s[k * 8 + 2 * qq + 1];
        }
        z1s[row * 9 + 2 * qq]     = fmaxf(z0, 0.f);
        z1s[row * 9 + 2 * qq + 1] = fmaxf(z1v, 0.f);
    }
    if (qq == 0 && valid) {
        float rv[8];
        #pragma unroll
        for (int c = 0; c < 8; c++) rv[c] = tile[row * 65 + c];
        float m = rv[0];
        #pragma unroll
        for (int c = 1; c < 8; c++) m = fmaxf(m, rv[c]);
        float ex[8], s = 0.f;
        #pragma unroll
        for (int c = 0; c < 8; c++) { ex[c] = __expf(rv[c] - m); s += ex[c]; }
        float inv = 1.f / s;
        float4 v0 = {ex[0] * inv, ex[1] * inv, ex[2] * inv, ex[3] * inv};
        float4 v1 = {ex[4] * inv, ex[5] * inv, ex[6] * inv, ex[7] * inv};
        *(float4*)&mid_out[(size_t)gm * 8]     = v0;
        *(float4*)&mid_out[(size_t)gm * 8 + 4] = v1;
    }
    __syncthreads();
    if (qq == 0 && valid) {
        float z20 = b2s[0], z21 = b2s[1];
        #pragma unroll
        for (int o = 0; o < 8; o++) {
            float z = z1s[row * 9 + o];
            z20 += z * w2s[o * 2];
            z21 += z * w2s[o * 2 + 1];
        }
        z20 = fmaxf(z20, 0.f);
        z21 = fmaxf(z21, 0.f);
        int b = batch[gm];
        atomicMax(&pool_s[b * 2 + 0], __float_as_uint(z20));
        atomicMax(&pool_s[b * 2 + 1], __float_as_uint(z21));
    }
    __syncthreads();
    if (t < N_GRAPHS * 2) {
        unsigned int v = pool_s[t];
        if (v) atomicMax(&pooled[t], v);
    }
    __syncthreads();
    if (t == 0) {
        __threadfence();
        unsigned int prev = atomicAdd(done_cnt, 1u);
        amLast = (prev == gridDim.x - 1) ? 1u : 0u;
    }
    __syncthreads();
    if (amLast) {
        if (t < N_GRAPHS * 2) fin[t] = __uint_as_float(atomicMax(&pooled[t], 0u));
        __syncthreads();
        if (t < N_GRAPHS) {
            float v0 = fin[2 * t], v1 = fin[2 * t + 1];
            float m = fmaxf(v0, v1);
            float e0 = __expf(v0 - m), e1 = __expf(v1 - m);
            float s = e0 + e1;
            fin_out[2 * t]     = e0 / s;
            fin_out[2 * t + 1] = e1 / s;
        }
    }
}

// ---------------- launch ----------------
extern "C" void kernel_launch(void* const* d_in, const int* in_sizes, int n_in,
                              void* d_out, int out_size, void* d_ws, size_t ws_size,
                              hipStream_t stream) {
    const float* x    = (const float*)d_in[0];
    const int*   ei   = (const int*)d_in[1];
    const int*   batch= (const int*)d_in[2];
    const float* W1r  = (const float*)d_in[3];
    const float* W1l  = (const float*)d_in[4];
    const float* b1   = (const float*)d_in[5];
    const float* W2r  = (const float*)d_in[6];
    const float* W2l  = (const float*)d_in[7];
    const float* b2   = (const float*)d_in[8];
    const float* fc1w = (const float*)d_in[9];
    const float* fc1b = (const float*)d_in[10];
    const float* fc2w = (const float*)d_in[11];
    const float* fc2b = (const float*)d_in[12];

    const int* src = ei;
    const int* dst = ei + N_EDGES;

    char* ws = (char*)d_ws;
    int*    cur    = (int*)(ws + OFF_CUR);
    unsigned int* pooled   = (unsigned int*)(ws + OFF_POOLED);
    unsigned int* done_cnt = (unsigned int*)(ws + OFF_DONE);
    int2*   rows   = (int2*)(ws + OFF_ROWS);
    int*    esrc   = (int*)(ws + OFF_ESRC);
    int*    epk    = (int*)(ws + OFF_EPK);
    f16_t*  xh     = (f16_t*)(ws + OFF_XH);
    f16_t*  h1h    = (f16_t*)(ws + OFF_H1H);
    f16_t*  aggh   = (f16_t*)(ws + OFF_AGGH);
    f16_t*  Wt1    = (f16_t*)(ws + OFF_WT1);
    f16_t*  Wt2    = (f16_t*)(ws + OFF_WT2);

    float* mid_out = (float*)d_out;                       // 50000*8
    float* fin_out = (float*)d_out + (size_t)N_NODES * 8; // 64*2

    init_cast_wcast_kernel<<<CAST_BLKS + 2, 256, 0, stream>>>(
        x, xh, W1r, W1l, Wt1, W2r, W2l, Wt2, cur, pooled, done_cnt);
    hist_scatter_kernel<<<HS_BLOCKS, 256, 0, stream>>>(src, dst, cur, epk);
    fine_sort_kernel<<<NBKT, 256, 0, stream>>>(epk, cur, esrc, rows);

    const int AB = (N_NODES + 3) / 4;     // 4 waves (nodes) per block
    const int GB = (N_NODES + 63) / 64;   // 782

    // layer 1
    agg_kernel<<<AB, 256, 0, stream>>>(xh, rows, esrc, aggh);
    gemm_mfma_kernel<<<GB, 256, 0, stream>>>(xh, aggh, Wt1, b1, h1h);
    // layer 2 + head + pooling + final (fused)
    agg_kernel<<<AB, 256, 0, stream>>>(h1h, rows, esrc, aggh);
    gemm2_head_kernel<<<GB, 256, 0, stream>>>(h1h, aggh, Wt2, b2, batch,
                                              fc1w, fc1b, fc2w, fc2b,
                                              mid_out, pooled, done_cnt, fin_out);
}

// Round 12
// 108.586 us; speedup vs baseline: 6.3351x; 1.0535x over previous
//
#include <hip/hip_runtime.h>
#include <hip/hip_fp16.h>

typedef _Float16 f16_t;
typedef _Float16 f16x8 __attribute__((ext_vector_type(8)));
typedef float f32x4 __attribute__((ext_vector_type(4)));

#define N_NODES 50000
#define N_EDGES 800000
#define C 64
#define N_GRAPHS 64

#define NBKT 256                   // coarse buckets (196 nodes each)
#define NPB 196
#define BKT_CAP 4096               // slots per bucket (mean 3125 + 17 sigma)
#define HS_BLOCKS 256              // hist+scatter grid
#define HS_EPB (N_EDGES / HS_BLOCKS)   // 3125 (exact)
#define CAST_BLKS 1563             // ceil(400000/256)
#define CUR_STRIDE 16              // pad cursors to one 64B line each

// ---------------- workspace layout (bytes; ws ~256 MB) ----------------
#define OFF_CUR    0u          // 256 cursors, padded x16 ints (16 KB)
#define OFF_POOLED 16384u      // N_GRAPHS*2 uints
#define OFF_DONE   16896u      // completion counter
#define OFF_ROWS   17152u      // N_NODES int2 {beg,end} (400 KB)
#define OFF_ESRC   417280u     // NBKT*BKT_CAP ints (4 MB), padded CSR
#define OFF_EPK    4611584u    // NBKT*BKT_CAP ints (4 MB)
#define OFF_XH     8805888u    // x fp16 (6.4 MB)
#define OFF_H1H    15205888u   // h1 fp16 (6.4 MB)
#define OFF_WT1    21605888u   // Wcat1^T fp16 (16 KB)
#define OFF_WT2    21622272u   // Wcat2^T fp16 (16 KB)
// total ~21.6 MB

__device__ __forceinline__ unsigned pack2h(float x, float y) {
    __half2 h = __floats2half2_rn(x, y);
    return *reinterpret_cast<unsigned*>(&h);
}

// ---------------- k0: init (block 0) + x->fp16 cast + W transpose/cast ----------------
__global__ __launch_bounds__(256) void init_cast_wcast_kernel(
        const float* __restrict__ x, f16_t* __restrict__ xh,
        const float* __restrict__ W1r, const float* __restrict__ W1l, f16_t* __restrict__ Wt1,
        const float* __restrict__ W2r, const float* __restrict__ W2l, f16_t* __restrict__ Wt2,
        int* __restrict__ cur, unsigned int* __restrict__ pooled,
        unsigned int* __restrict__ done_cnt) {
    __shared__ float w0[64 * 64];
    __shared__ float w1[64 * 64];
    const int blk = blockIdx.x;
    const int t = threadIdx.x;
    if (blk < CAST_BLKS) {
        if (blk == 0) {
            #pragma unroll
            for (int k = 0; k < CUR_STRIDE; k++) cur[k * 256 + t] = 0;
            if (t < N_GRAPHS * 2) pooled[t] = 0u;
            if (t == 0) *done_cnt = 0u;
        }
        const int i = blk * 256 + t;
        if (i < N_NODES * C / 8) {
            const float4* p = (const float4*)(x + (size_t)i * 8);
            float4 a = p[0], b = p[1];
            uint4 w;
            w.x = pack2h(a.x, a.y);
            w.y = pack2h(a.z, a.w);
            w.z = pack2h(b.x, b.y);
            w.w = pack2h(b.z, b.w);
            *(uint4*)(xh + (size_t)i * 8) = w;
        }
    } else {
        const int which = blk - CAST_BLKS;   // 0 or 1
        const float* Wr = which ? W2r : W1r;
        const float* Wl = which ? W2l : W1l;
        f16_t* Wt = which ? Wt2 : Wt1;
        for (int i = t * 4; i < 4096; i += 1024) {
            *(float4*)&w0[i] = *(const float4*)&Wr[i];
            *(float4*)&w1[i] = *(const float4*)&Wl[i];
        }
        __syncthreads();
        const int n = t >> 2, q = t & 3;
        for (int kk = q * 32; kk < q * 32 + 32; kk++) {
            float v = (kk < 64) ? w0[kk * 64 + n] : w1[(kk - 64) * 64 + n];
            Wt[n * 128 + kk] = (f16_t)v;
        }
    }
}

// ---------------- k1: fused hist + reserve + scatter (padded buckets) ----------------
__global__ __launch_bounds__(256) void hist_scatter_kernel(const int* __restrict__ src,
                                                           const int* __restrict__ dst,
                                                           int* __restrict__ cur,
                                                           int* __restrict__ epk) {
    __shared__ int h[NBKT];
    __shared__ int base_s[NBKT];
    const int t = threadIdx.x;
    const int blk = blockIdx.x;
    h[t] = 0;
    __syncthreads();
    const int beg = blk * HS_EPB;
    for (int i = beg + t; i < beg + HS_EPB; i += 256)
        atomicAdd(&h[dst[i] / NPB], 1);
    __syncthreads();
    {
        int hv = h[t];
        int old = hv ? atomicAdd(&cur[t * CUR_STRIDE], hv) : 0;
        base_s[t] = t * BKT_CAP + old;
        h[t] = 0;   // reuse as local cursor
    }
    __syncthreads();
    for (int i = beg + t; i < beg + HS_EPB; i += 256) {
        int d = dst[i];
        int b = d / NPB;
        int off = atomicAdd(&h[b], 1);
        int pos = base_s[b] + off;
        if (pos < (b + 1) * BKT_CAP)
            epk[pos] = src[i] | ((d - b * NPB) << 16);
    }
}

// ---------------- k2: fine sort within bucket -> padded CSR (esrc + rows) ----------------
__global__ __launch_bounds__(256) void fine_sort_kernel(const int* __restrict__ epk,
                                                        const int* __restrict__ cur,
                                                        int* __restrict__ esrc,
                                                        int2* __restrict__ rows) {
    __shared__ int cnt_s[NPB];
    __shared__ int s[256];
    __shared__ int staged[BKT_CAP];
    const int t = threadIdx.x;
    const int blk = blockIdx.x;
    const int base = blk * BKT_CAP;
    int n = cur[blk * CUR_STRIDE];
    if (n > BKT_CAP) n = BKT_CAP;
    if (t < NPB) cnt_s[t] = 0;
    __syncthreads();
    for (int e = t; e < n; e += 256)
        atomicAdd(&cnt_s[((unsigned)epk[base + e]) >> 16], 1);
    __syncthreads();
    int v = (t < NPB) ? cnt_s[t] : 0;
    s[t] = v;
    __syncthreads();
    for (int off = 1; off < 256; off <<= 1) {
        int x = (t >= off) ? s[t - off] : 0;
        __syncthreads();
        if (t >= off) s[t] += x;
        __syncthreads();
    }
    int excl = s[t] - v;
    const int node = blk * NPB + t;
    if (t < NPB) {
        cnt_s[t] = excl;
        if (node < N_NODES) {
            int2 be; be.x = base + excl; be.y = base + excl + v;
            rows[node] = be;
        }
    }
    __syncthreads();
    for (int e = t; e < n; e += 256) {
        int pk = epk[base + e];
        int pos = atomicAdd(&cnt_s[((unsigned)pk) >> 16], 1);
        staged[pos] = pk & 0xFFFF;
    }
    __syncthreads();
    for (int i = t; i < n; i += 256) esrc[base + i] = staged[i];  // coalesced
}

// ======== fused per-block aggregation (into swizzled LDS) + staging + MFMA ========
// Block = 1024 threads = 16 waves, 64 output rows. Wave w aggregates 4 nodes
// (16 lanes x 8B x 4 edge slots), storing fp16 sums into the k=64..127 half of
// Als. x/W staging loads are issued FIRST so their latency overlaps the gather.
__device__ __forceinline__ void stage_and_mfma(
        const f16_t* __restrict__ Hsrc,     // gather + A-operand source (row-major 64)
        const int2* __restrict__ rows, const int* __restrict__ esrc,
        const f16_t* __restrict__ Wt, const float* __restrict__ bias,
        f16_t* Als, f16_t* Wls, int row0, int t, f32x4& acc,
        int& ncol, int& outrow0) {
    const int xr = t >> 4, xc = t & 15;              // x-part: 64 rows x 16 8B-chunks
    int gxr = row0 + xr; if (gxr > N_NODES - 1) gxr = N_NODES - 1;
    uint2 xv = *(const uint2*)(Hsrc + (size_t)gxr * 64 + xc * 4);
    uint4 wvv = *(const uint4*)(Wt + (t >> 4) * 128 + (t & 15) * 8);  // W: 16B/thread
    const int wv = t >> 6, lane = t & 63;
    const int slot = lane >> 4, j = lane & 15;
    const uint2* hw = (const uint2*)Hsrc;
    #pragma unroll
    for (int i = 0; i < 4; i++) {
        const int n = row0 + wv * 4 + i;
        float s0 = 0.f, s1 = 0.f, s2 = 0.f, s3 = 0.f;
        if (n < N_NODES) {
            int2 be = rows[n];
            int beg = be.x, end = be.y;
            int e = beg;
            for (; e + 16 <= end; e += 16) {
                int i0 = esrc[e + slot];
                int i1 = esrc[e + 4 + slot];
                int i2 = esrc[e + 8 + slot];
                int i3 = esrc[e + 12 + slot];
                uint2 u0 = hw[(size_t)i0 * 16 + j];
                uint2 u1 = hw[(size_t)i1 * 16 + j];
                uint2 u2 = hw[(size_t)i2 * 16 + j];
                uint2 u3 = hw[(size_t)i3 * 16 + j];
                float2 a, b;
                a = __half22float2(*(__half2*)&u0.x); b = __half22float2(*(__half2*)&u0.y);
                s0 += a.x; s1 += a.y; s2 += b.x; s3 += b.y;
                a = __half22float2(*(__half2*)&u1.x); b = __half22float2(*(__half2*)&u1.y);
                s0 += a.x; s1 += a.y; s2 += b.x; s3 += b.y;
                a = __half22float2(*(__half2*)&u2.x); b = __half22float2(*(__half2*)&u2.y);
                s0 += a.x; s1 += a.y; s2 += b.x; s3 += b.y;
                a = __half22float2(*(__half2*)&u3.x); b = __half22float2(*(__half2*)&u3.y);
                s0 += a.x; s1 += a.y; s2 += b.x; s3 += b.y;
            }
            for (; e + 4 <= end; e += 4) {
                int i0 = esrc[e + slot];
                uint2 u = hw[(size_t)i0 * 16 + j];
                float2 a = __half22float2(*(__half2*)&u.x);
                float2 b = __half22float2(*(__half2*)&u.y);
                s0 += a.x; s1 += a.y; s2 += b.x; s3 += b.y;
            }
            int rem = end - e;
            if (slot < rem) {
                int i0 = esrc[e + slot];
                uint2 u = hw[(size_t)i0 * 16 + j];
                float2 a = __half22float2(*(__half2*)&u.x);
                float2 b = __half22float2(*(__half2*)&u.y);
                s0 += a.x; s1 += a.y; s2 += b.x; s3 += b.y;
            }
        }
        s0 += __shfl_xor(s0, 16); s1 += __shfl_xor(s1, 16);
        s2 += __shfl_xor(s2, 16); s3 += __shfl_xor(s3, 16);
        s0 += __shfl_xor(s0, 32); s1 += __shfl_xor(s1, 32);
        s2 += __shfl_xor(s2, 32); s3 += __shfl_xor(s3, 32);
        if (slot == 0) {
            const int r = wv * 4 + i;
            uint2 o; o.x = pack2h(s0, s1); o.y = pack2h(s2, s3);
            *(uint2*)((char*)Als + r * 256 + ((128 + j * 8) ^ ((r & 7) << 4))) = o;
        }
    }
    // x / W -> LDS (swizzled)
    *(uint2*)((char*)Als + xr * 256 + ((xc * 8) ^ ((xr & 7) << 4))) = xv;
    {
        const int wn = t >> 4, wc8 = t & 15;
        *(uint4*)((char*)Wls + wn * 256 + ((wc8 * 16) ^ ((wn & 7) << 4))) = wvv;
    }
    __syncthreads();
    // MFMA: wave wv -> (wr, wc) 16x16 tile, k = 128
    const int lr = lane & 15, kh = lane >> 4;
    const int wr = wv >> 2, wc = wv & 3;
    const int arow = wr * 16 + lr;
    ncol = wc * 16 + lr;
    outrow0 = row0 + wr * 16 + kh * 4;
    float bv = bias[ncol];
    acc = (f32x4){bv, bv, bv, bv};
    #pragma unroll
    for (int kt = 0; kt < 4; kt++) {
        const int kb = (kt * 32 + kh * 8) * 2;
        f16x8 a = *(const f16x8*)((const char*)Als + arow * 256 + (kb ^ ((arow & 7) << 4)));
        f16x8 b = *(const f16x8*)((const char*)Wls + ncol * 256 + (kb ^ ((ncol & 7) << 4)));
        acc = __builtin_amdgcn_mfma_f32_16x16x32_f16(a, b, acc, 0, 0, 0);
    }
}

// ---------------- layer 1: fused agg + GEMM -> h1 fp16 ----------------
__global__ __launch_bounds__(1024) void layer1_kernel(const f16_t* __restrict__ xh,
                                                      const int2* __restrict__ rows,
                                                      const int* __restrict__ esrc,
                                                      const f16_t* __restrict__ Wt,
                                                      const float* __restrict__ bias,
                                                      f16_t* __restrict__ h1h) {
    __shared__ f16_t Als[64 * 128];
    __shared__ f16_t Wls[64 * 128];
    const int t = threadIdx.x;
    const int row0 = blockIdx.x * 64;
    f32x4 acc; int ncol, outrow0;
    stage_and_mfma(xh, rows, esrc, Wt, bias, Als, Wls, row0, t, acc, ncol, outrow0);
    #pragma unroll
    for (int rr = 0; rr < 4; rr++) {
        const int gm = outrow0 + rr;
        if (gm < N_NODES)
            h1h[(size_t)gm * 64 + ncol] = (f16_t)fmaxf(acc[rr], 0.f);
    }
}

// ---------------- layer 2: fused agg + GEMM + head + pooling + final ----------------
__global__ __launch_bounds__(1024) void layer2_head_kernel(
        const f16_t* __restrict__ h1h,
        const int2* __restrict__ rows, const int* __restrict__ esrc,
        const f16_t* __restrict__ Wt, const float* __restrict__ bias,
        const int* __restrict__ batch,
        const float* __restrict__ fc1w, const float* __restrict__ fc1b,
        const float* __restrict__ fc2w, const float* __restrict__ fc2b,
        float* __restrict__ mid_out, unsigned int* __restrict__ pooled,
        unsigned int* __restrict__ done_cnt, float* __restrict__ fin_out) {
    __shared__ f16_t Als[64 * 128];
    __shared__ f16_t Wls[64 * 128];
    __shared__ float tile[64 * 65];
    __shared__ float w1s[512];
    __shared__ float z1s[64 * 9];
    __shared__ float b1s[8];
    __shared__ float w2s[16];
    __shared__ float b2s[2];
    __shared__ unsigned int pool_s[N_GRAPHS * 2];
    __shared__ unsigned int amLast;
    __shared__ float fin[N_GRAPHS * 2];
    const int t = threadIdx.x;
    const int row0 = blockIdx.x * 64;
    if (t < 512) w1s[t] = fc1w[t];
    if (t >= 512 && t < 520) b1s[t - 512] = fc1b[t - 512];
    if (t >= 520 && t < 536) w2s[t - 520] = fc2w[t - 520];
    if (t >= 536 && t < 538) b2s[t - 536] = fc2b[t - 536];
    if (t >= 544 && t < 544 + N_GRAPHS * 2) pool_s[t - 544] = 0u;
    f32x4 acc; int ncol, outrow0;
    stage_and_mfma(h1h, rows, esrc, Wt, bias, Als, Wls, row0, t, acc, ncol, outrow0);
    // h2 tile -> LDS (relu)
    #pragma unroll
    for (int rr = 0; rr < 4; rr++)
        tile[(outrow0 - row0 + rr) * 65 + ncol] = fmaxf(acc[rr], 0.f);
    __syncthreads();
    const int row = t & 63, qq = t >> 6;   // qq 0..15; head uses qq<4
    const int gm = row0 + row;
    const bool valid = gm < N_NODES;
    if (qq < 4) {
        float z0 = b1s[2 * qq], z1v = b1s[2 * qq + 1];
        for (int k = 0; k < 64; k++) {
            float a = tile[row * 65 + k];
            z0  += a * w1s[k * 8 + 2 * qq];
            z1v += a * w1s[k * 8 + 2 * qq + 1];
        }
        z1s[row * 9 + 2 * qq]     = fmaxf(z0, 0.f);
        z1s[row * 9 + 2 * qq + 1] = fmaxf(z1v, 0.f);
    }
    if (qq == 4 && valid) {   // mid softmax (done by wave group 4, overlaps fc1)
        float rv[8];
        #pragma unroll
        for (int c = 0; c < 8; c++) rv[c] = tile[row * 65 + c];
        float m = rv[0];
        #pragma unroll
        for (int c = 1; c < 8; c++) m = fmaxf(m, rv[c]);
        float ex[8], s = 0.f;
        #pragma unroll
        for (int c = 0; c < 8; c++) { ex[c] = __expf(rv[c] - m); s += ex[c]; }
        float inv = 1.f / s;
        float4 v0 = {ex[0] * inv, ex[1] * inv, ex[2] * inv, ex[3] * inv};
        float4 v1 = {ex[4] * inv, ex[5] * inv, ex[6] * inv, ex[7] * inv};
        *(float4*)&mid_out[(size_t)gm * 8]     = v0;
        *(float4*)&mid_out[(size_t)gm * 8 + 4] = v1;
    }
    __syncthreads();
    if (qq == 0 && valid) {   // fc2 + LDS pool
        float z20 = b2s[0], z21 = b2s[1];
        #pragma unroll
        for (int o = 0; o < 8; o++) {
            float z = z1s[row * 9 + o];
            z20 += z * w2s[o * 2];
            z21 += z * w2s[o * 2 + 1];
        }
        z20 = fmaxf(z20, 0.f);
        z21 = fmaxf(z21, 0.f);
        int b = batch[gm];
        atomicMax(&pool_s[b * 2 + 0], __float_as_uint(z20));
        atomicMax(&pool_s[b * 2 + 1], __float_as_uint(z21));
    }
    __syncthreads();
    if (t < N_GRAPHS * 2) {
        unsigned int v = pool_s[t];
        if (v) atomicMax(&pooled[t], v);
    }
    __syncthreads();
    if (t == 0) {
        __threadfence();
        unsigned int prev = atomicAdd(done_cnt, 1u);
        amLast = (prev == gridDim.x - 1) ? 1u : 0u;
    }
    __syncthreads();
    if (amLast) {
        if (t < N_GRAPHS * 2) fin[t] = __uint_as_float(atomicMax(&pooled[t], 0u));
        __syncthreads();
        if (t < N_GRAPHS) {
            float v0 = fin[2 * t], v1 = fin[2 * t + 1];
            float m = fmaxf(v0, v1);
            float e0 = __expf(v0 - m), e1 = __expf(v1 - m);
            float s = e0 + e1;
            fin_out[2 * t]     = e0 / s;
            fin_out[2 * t + 1] = e1 / s;
        }
    }
}

// ---------------- launch ----------------
extern "C" void kernel_launch(void* const* d_in, const int* in_sizes, int n_in,
                              void* d_out, int out_size, void* d_ws, size_t ws_size,
                              hipStream_t stream) {
    const float* x    = (const float*)d_in[0];
    const int*   ei   = (const int*)d_in[1];
    const int*   batch= (const int*)d_in[2];
    const float* W1r  = (const float*)d_in[3];
    const float* W1l  = (const float*)d_in[4];
    const float* b1   = (const float*)d_in[5];
    const float* W2r  = (const float*)d_in[6];
    const float* W2l  = (const float*)d_in[7];
    const float* b2   = (const float*)d_in[8];
    const float* fc1w = (const float*)d_in[9];
    const float* fc1b = (const float*)d_in[10];
    const float* fc2w = (const float*)d_in[11];
    const float* fc2b = (const float*)d_in[12];

    const int* src = ei;
    const int* dst = ei + N_EDGES;

    char* ws = (char*)d_ws;
    int*    cur    = (int*)(ws + OFF_CUR);
    unsigned int* pooled   = (unsigned int*)(ws + OFF_POOLED);
    unsigned int* done_cnt = (unsigned int*)(ws + OFF_DONE);
    int2*   rows   = (int2*)(ws + OFF_ROWS);
    int*    esrc   = (int*)(ws + OFF_ESRC);
    int*    epk    = (int*)(ws + OFF_EPK);
    f16_t*  xh     = (f16_t*)(ws + OFF_XH);
    f16_t*  h1h    = (f16_t*)(ws + OFF_H1H);
    f16_t*  Wt1    = (f16_t*)(ws + OFF_WT1);
    f16_t*  Wt2    = (f16_t*)(ws + OFF_WT2);

    float* mid_out = (float*)d_out;                       // 50000*8
    float* fin_out = (float*)d_out + (size_t)N_NODES * 8; // 64*2

    init_cast_wcast_kernel<<<CAST_BLKS + 2, 256, 0, stream>>>(
        x, xh, W1r, W1l, Wt1, W2r, W2l, Wt2, cur, pooled, done_cnt);
    hist_scatter_kernel<<<HS_BLOCKS, 256, 0, stream>>>(src, dst, cur, epk);
    fine_sort_kernel<<<NBKT, 256, 0, stream>>>(epk, cur, esrc, rows);

    const int GB = (N_NODES + 63) / 64;   // 782

    layer1_kernel<<<GB, 1024, 0, stream>>>(xh, rows, esrc, Wt1, b1, h1h);
    layer2_head_kernel<<<GB, 1024, 0, stream>>>(h1h, rows, esrc, Wt2, b2, batch,
                                                fc1w, fc1b, fc2w, fc2b,
                                                mid_out, pooled, done_cnt, fin_out);
}